// Round 10
// baseline (867.492 us; speedup 1.0000x reference)
//
#include <hip/hip_runtime.h>
#include <hip/hip_bf16.h>

#define U_CNT 339
#define S_CNT 5825
#define N_CNT 6164          // U + S
#define D_DIM 128
#define R_DIM 32
#define B_CNT 500000
#define M_EDGE 400000       // 2*NNZ (symmetrized)
#define H_DIM 64
#define LN_EPS 1e-5f

// dense adjacency (bf16), padded strides for dword-pair access
#define BD_STRIDE  5826     // Bd  rows: 340 x 5826 ushorts
#define BDT_STRIDE 340      // BdT rows: 5832 x 340 ushorts
#define BD_USHORTS  (340 * BD_STRIDE)
#define BDT_USHORTS (5832 * BDT_STRIDE)
#define BALL_USHORTS (BD_USHORTS + BDT_USHORTS)      // 3,963,720
#define BZ_QUADS ((BALL_USHORTS * 2 + 15) / 16)      // uint4 count for zeroing

// fp32 weight-block offsets (elements)
#define WF_B1   4096
#define WF_G1   4160
#define WF_BE1  4224
#define WF_B2   4288
#define WF_G2   4352
#define WF_BE2  4416
#define WF_W3   4480
#define WF_B3   4544
#define WF_TOT  4545

typedef __hip_bfloat16 bf16;
typedef __attribute__((ext_vector_type(8))) short sh8;   // 8 bf16 = 4 VGPRs (MFMA A/B frag)
typedef __attribute__((ext_vector_type(4))) float f4v;   // MFMA C/D frag

__device__ __forceinline__ float b2f(bf16 x) { return __bfloat162float(x); }
__device__ __forceinline__ short f2bs(float f) {
    union { bf16 b; short s; } u;
    u.b = __float2bfloat16(f);
    return u.s;
}
__device__ __forceinline__ float bu2f(unsigned int lo16) {   // bf16 bits -> f32
    return __uint_as_float(lo16 << 16);
}

// generic float-input load: isf32 selects fp32 vs bf16 interpretation
__device__ __forceinline__ float ldf(const void* p, long i, int isf32) {
    return isf32 ? ((const float*)p)[i] : b2f(((const bf16*)p)[i]);
}

// ---------- init: zero dense adjacency + dtype detect ----------
__global__ void k_init(const void* __restrict__ uE, uint4* __restrict__ Ball,
                       int* __restrict__ flag) {
    int i = blockIdx.x * 256 + threadIdx.x;
    if (i < BZ_QUADS) Ball[i] = make_uint4(0u, 0u, 0u, 0u);
    if (blockIdx.x == 0 && threadIdx.x < 64) {
        const unsigned short* p = (const unsigned short*)uE;
        unsigned short v = p[2 * threadIdx.x];       // even bf16 element
        int e = (v >> 7) & 0xFF;                     // bf16 exponent field
        unsigned long long m = __ballot(e >= 127);   // impossible for Xavier bf16
        if (threadIdx.x == 0) flag[0] = (m != 0ull) ? 1 : 0;  // 1 => fp32 buffers
    }
}

// ---------- concat embeddings to fp32 [N,D] + dense-B scatter (NO atomics) ----------
__global__ void k_pre(const void* __restrict__ uE, const void* __restrict__ iE,
                      float* __restrict__ E, const int* __restrict__ rows,
                      const int* __restrict__ cols, const void* __restrict__ vals,
                      unsigned short* __restrict__ Bd, unsigned short* __restrict__ BdT,
                      const int* __restrict__ flag) {
    int i = blockIdx.x * 256 + threadIdx.x;
    int isf32 = flag[0];
    const int T1 = N_CNT * D_DIM;
    if (i < T1) {
        const int uTot = U_CNT * D_DIM;
        E[i] = (i < uTot) ? ldf(uE, i, isf32) : ldf(iE, i - uTot, isf32);
    }
    if (i < M_EDGE) {
        int r = rows[i], c = cols[i];
        float v = ldf(vals, i, isf32);               // bf16 inputs -> lossless
        unsigned short hv = (unsigned short)f2bs(v);
        if (r < U_CNT) Bd[r * BD_STRIDE + (c - U_CNT)] = hv;
        else           BdT[(r - U_CNT) * BDT_STRIDE + c] = hv;
    }
}

// ---------- one GCN hop: dense matvec both sides, fp32 accumulate ----------
// blocks [0,170): u-side (2 u x 128 d), K=5825 via packed bf16 pairs;
// blocks [170,899): s-side (8 s x 128 d), K=339.
__global__ void __launch_bounds__(256)
k_hop(const float* __restrict__ Ein, float* __restrict__ Eout,
      const unsigned short* __restrict__ Bd, const unsigned short* __restrict__ BdT) {
    int tid = threadIdx.x;
    int d = tid & 127;
    if (blockIdx.x < 170) {
        int u = blockIdx.x * 2 + (tid >> 7);
        if (u >= U_CNT) return;
        const unsigned short* br = Bd + u * BD_STRIDE;  // wave-uniform row
        const float* Eb = Ein + U_CNT * D_DIM + d;
        float a0 = 0, a1 = 0, a2 = 0, a3 = 0;
        int s = 0;
        #pragma unroll 2
        for (; s + 4 <= S_CNT; s += 4) {
            unsigned int w0 = *(const unsigned int*)(br + s);
            unsigned int w1 = *(const unsigned int*)(br + s + 2);
            float e0 = Eb[(s + 0) * D_DIM], e1 = Eb[(s + 1) * D_DIM];
            float e2 = Eb[(s + 2) * D_DIM], e3 = Eb[(s + 3) * D_DIM];
            a0 = fmaf(__uint_as_float(w0 << 16), e0, a0);
            a1 = fmaf(__uint_as_float(w0 & 0xffff0000u), e1, a1);
            a2 = fmaf(__uint_as_float(w1 << 16), e2, a2);
            a3 = fmaf(__uint_as_float(w1 & 0xffff0000u), e3, a3);
        }
        for (; s < S_CNT; ++s)                        // 5825 % 4 == 1
            a0 = fmaf(bu2f(br[s]), Eb[s * D_DIM], a0);
        Eout[u * D_DIM + d] = (a0 + a1) + (a2 + a3);
    } else {
        int sg = tid >> 7;
        int s0 = (blockIdx.x - 170) * 8 + sg * 4;     // rows s0..s0+3 (padded reads OK)
        const float* Eb = Ein + d;
        const unsigned short* r0 = BdT + (s0 + 0) * BDT_STRIDE;
        const unsigned short* r1 = BdT + (s0 + 1) * BDT_STRIDE;
        const unsigned short* r2 = BdT + (s0 + 2) * BDT_STRIDE;
        const unsigned short* r3 = BdT + (s0 + 3) * BDT_STRIDE;
        float a0 = 0, a1 = 0, a2 = 0, a3 = 0;
        int u = 0;
        #pragma unroll 2
        for (; u + 2 <= U_CNT; u += 2) {
            float e0 = Eb[u * D_DIM], e1 = Eb[(u + 1) * D_DIM];
            unsigned int w0 = *(const unsigned int*)(r0 + u);
            unsigned int w1 = *(const unsigned int*)(r1 + u);
            unsigned int w2 = *(const unsigned int*)(r2 + u);
            unsigned int w3 = *(const unsigned int*)(r3 + u);
            a0 = fmaf(__uint_as_float(w0 << 16), e0, a0);
            a0 = fmaf(__uint_as_float(w0 & 0xffff0000u), e1, a0);
            a1 = fmaf(__uint_as_float(w1 << 16), e0, a1);
            a1 = fmaf(__uint_as_float(w1 & 0xffff0000u), e1, a1);
            a2 = fmaf(__uint_as_float(w2 << 16), e0, a2);
            a2 = fmaf(__uint_as_float(w2 & 0xffff0000u), e1, a2);
            a3 = fmaf(__uint_as_float(w3 << 16), e0, a3);
            a3 = fmaf(__uint_as_float(w3 & 0xffff0000u), e1, a3);
        }
        {                                             // tail u = 338
            float e0 = Eb[338 * D_DIM];
            a0 = fmaf(bu2f(r0[338]), e0, a0);
            a1 = fmaf(bu2f(r1[338]), e0, a1);
            a2 = fmaf(bu2f(r2[338]), e0, a2);
            a3 = fmaf(bu2f(r3[338]), e0, a3);
        }
        float* Eo = Eout + (U_CNT + s0) * D_DIM + d;
        if (s0 + 0 < S_CNT) Eo[0 * D_DIM] = a0;
        if (s0 + 1 < S_CNT) Eo[1 * D_DIM] = a1;
        if (s0 + 2 < S_CNT) Eo[2 * D_DIM] = a2;
        if (s0 + 3 < S_CNT) Eo[3 * D_DIM] = a3;
    }
}

// ---------- blocks 0,1: P = Hyperᵀ(Hyper @ W1part); block 2: weight prep ----------
// Block 2 packs W2 into bf16 MFMA B-fragments (B[k=quad*8+j][n=lane&15]) + fp32 Wf.
__global__ void k_hyperP(const void* __restrict__ uHy, const void* __restrict__ iHy,
                         const void* __restrict__ W1, const void* __restrict__ W2,
                         const void* __restrict__ b1, const void* __restrict__ g1,
                         const void* __restrict__ be1, const void* __restrict__ b2,
                         const void* __restrict__ g2, const void* __restrict__ be2,
                         const void* __restrict__ W3, const void* __restrict__ b3,
                         float* __restrict__ P, float* __restrict__ Wf,
                         unsigned short* __restrict__ Wb,
                         const int* __restrict__ flag) {
    int isf32 = flag[0];
    if (blockIdx.x == 2) {                            // weight prep
        for (int i = threadIdx.x; i < 4096; i += 256) {
            int j = i & 7, lane = (i >> 3) & 63, kh = (i >> 9) & 1, t = i >> 10;
            int k = kh * 32 + ((lane >> 4) & 3) * 8 + j;
            int n = t * 16 + (lane & 15);
            Wb[i] = (unsigned short)f2bs(ldf(W2, k * 64 + n, isf32));
        }
        for (int i = threadIdx.x; i < WF_TOT - 4096; i += 256) {
            int g = 4096 + i;
            float v;
            if      (g < WF_G1)  v = ldf(b1,  g - WF_B1,   isf32);
            else if (g < WF_BE1) v = ldf(g1,  g - WF_G1,   isf32);
            else if (g < WF_B2)  v = ldf(be1, g - WF_BE1,  isf32);
            else if (g < WF_G2)  v = ldf(b2,  g - WF_B2,   isf32);
            else if (g < WF_BE2) v = ldf(g2,  g - WF_G2,   isf32);
            else if (g < WF_W3)  v = ldf(be2, g - WF_BE2,  isf32);
            else if (g < WF_B3)  v = ldf(W3,  g - WF_W3,   isf32);
            else                 v = ldf(b3,  0,           isf32);
            Wf[g] = v;
        }
        return;
    }
    int side = blockIdx.x;                            // 0 = user, 1 = service
    const void* Hy = side ? iHy : uHy;                // [32][128]
    long wbase = (long)side * D_DIM * H_DIM;          // rows [side*128 .. +128) of W1
    __shared__ float Hs[R_DIM * D_DIM];               // 16 KB
    __shared__ float T[R_DIM * H_DIM];                // 8 KB
    for (int idx = threadIdx.x; idx < R_DIM * D_DIM; idx += 256)
        Hs[idx] = ldf(Hy, idx, isf32);
    __syncthreads();
    for (int idx = threadIdx.x; idx < R_DIM * H_DIM; idx += 256) {
        int a = idx >> 6, j = idx & 63;
        float acc = 0.f;
        for (int d = 0; d < D_DIM; ++d)
            acc = fmaf(Hs[a * D_DIM + d], ldf(W1, wbase + d * H_DIM + j, isf32), acc);
        T[idx] = acc;
    }
    __syncthreads();
    for (int idx = threadIdx.x; idx < D_DIM * H_DIM; idx += 256) {
        int d = idx >> 6, j = idx & 63;
        float acc = 0.f;
        #pragma unroll
        for (int a = 0; a < R_DIM; ++a)
            acc = fmaf(Hs[a * D_DIM + d], T[a * H_DIM + j], acc);
        P[side * D_DIM * H_DIM + idx] = acc;
    }
}

// ---------- A[r,:] = E[r,:] @ P(side) (+ b1 folded into user rows) ----------
__global__ void k_A(const float* __restrict__ E, const float* __restrict__ P,
                    const float* __restrict__ Wf, float* __restrict__ A) {
    int r = blockIdx.x;
    int j = threadIdx.x;                              // 64 threads
    const float* Pr = P + ((r < U_CNT) ? 0 : D_DIM * H_DIM);
    const float* Er = E + r * D_DIM;                  // wave-uniform -> scalar loads
    float acc = (r < U_CNT) ? Wf[WF_B1 + j] : 0.f;
    #pragma unroll 8
    for (int d = 0; d < D_DIM; ++d)
        acc = fmaf(Er[d], Pr[d * H_DIM + j], acc);
    A[r * H_DIM + j] = acc;
}

// ---------- fused MLP via MFMA: one wave per 16 batch rows, NO LDS ----------
// (R9-verified: A[m=lane&15][k=quad*8+j]; B[k=quad*8+j][n=lane&15] pre-packed;
//  C/D col=lane&15, row=quad*4+reg. LN1 via xor-16/32; LN2 via xor-1..8.)
__global__ void __launch_bounds__(256)
HyperModel_65755949301857_kernel(
      const float* __restrict__ A, const int* __restrict__ userIdx,
      const int* __restrict__ servIdx, const float* __restrict__ Wf,
      const unsigned short* __restrict__ Wb,
      void* __restrict__ out, const int* __restrict__ flag) {
    int tid = threadIdx.x;
    int wave = tid >> 6, lane = tid & 63;
    long b0 = ((long)blockIdx.x * 4 + wave) * 16;
    if (b0 >= B_CNT) return;
    int isf32 = flag[0];
    int m = lane & 15, quad = lane >> 4;

    int r = (int)b0 + m;
    int ui = userIdx[r];
    int si = servIdx[r] + U_CNT;
    const float* Aur = A + (long)ui * 64;
    const float* Asr = A + (long)si * 64;

    float4 ul0 = *(const float4*)(Aur + quad * 8);
    float4 ul1 = *(const float4*)(Aur + quad * 8 + 4);
    float4 uh0 = *(const float4*)(Aur + 32 + quad * 8);
    float4 uh1 = *(const float4*)(Aur + 32 + quad * 8 + 4);
    float4 sl0 = *(const float4*)(Asr + quad * 8);
    float4 sl1 = *(const float4*)(Asr + quad * 8 + 4);
    float4 sh0 = *(const float4*)(Asr + 32 + quad * 8);
    float4 sh1 = *(const float4*)(Asr + 32 + quad * 8 + 4);
    float zl[8], zh[8];
    zl[0] = ul0.x + sl0.x; zl[1] = ul0.y + sl0.y; zl[2] = ul0.z + sl0.z; zl[3] = ul0.w + sl0.w;
    zl[4] = ul1.x + sl1.x; zl[5] = ul1.y + sl1.y; zl[6] = ul1.z + sl1.z; zl[7] = ul1.w + sl1.w;
    zh[0] = uh0.x + sh0.x; zh[1] = uh0.y + sh0.y; zh[2] = uh0.z + sh0.z; zh[3] = uh0.w + sh0.w;
    zh[4] = uh1.x + sh1.x; zh[5] = uh1.y + sh1.y; zh[6] = uh1.z + sh1.z; zh[7] = uh1.w + sh1.w;

    float s = 0.f, q = 0.f;
    #pragma unroll
    for (int j = 0; j < 8; ++j) {
        s += zl[j] + zh[j];
        q = fmaf(zl[j], zl[j], q);
        q = fmaf(zh[j], zh[j], q);
    }
    s += __shfl_xor(s, 16, 64); s += __shfl_xor(s, 32, 64);
    q += __shfl_xor(q, 16, 64); q += __shfl_xor(q, 32, 64);
    float mu = s * (1.f / 64.f);
    float rs = rsqrtf(q * (1.f / 64.f) - mu * mu + LN_EPS);
    float nm = -mu * rs;

    const float* G1l = Wf + WF_G1 + quad * 8;
    const float* BE1l = Wf + WF_BE1 + quad * 8;
    sh8 a0, a1;
    #pragma unroll
    for (int j = 0; j < 8; ++j) {
        float h0 = fmaxf(fmaf(fmaf(zl[j], rs, nm), G1l[j],      BE1l[j]),      0.f);
        float h1 = fmaxf(fmaf(fmaf(zh[j], rs, nm), G1l[32 + j], BE1l[32 + j]), 0.f);
        a0[j] = f2bs(h0);
        a1[j] = f2bs(h1);
    }

    const sh8* Bp = (const sh8*)Wb;
    sh8 b00 = Bp[0 * 64 + lane], b01 = Bp[1 * 64 + lane];
    sh8 b10 = Bp[2 * 64 + lane], b11 = Bp[3 * 64 + lane];
    sh8 b20 = Bp[4 * 64 + lane], b21 = Bp[5 * 64 + lane];
    sh8 b30 = Bp[6 * 64 + lane], b31 = Bp[7 * 64 + lane];
    f4v acc0 = {0.f, 0.f, 0.f, 0.f}, acc1 = acc0, acc2 = acc0, acc3 = acc0;
    acc0 = __builtin_amdgcn_mfma_f32_16x16x32_bf16(a0, b00, acc0, 0, 0, 0);
    acc0 = __builtin_amdgcn_mfma_f32_16x16x32_bf16(a1, b01, acc0, 0, 0, 0);
    acc1 = __builtin_amdgcn_mfma_f32_16x16x32_bf16(a0, b10, acc1, 0, 0, 0);
    acc1 = __builtin_amdgcn_mfma_f32_16x16x32_bf16(a1, b11, acc1, 0, 0, 0);
    acc2 = __builtin_amdgcn_mfma_f32_16x16x32_bf16(a0, b20, acc2, 0, 0, 0);
    acc2 = __builtin_amdgcn_mfma_f32_16x16x32_bf16(a1, b21, acc2, 0, 0, 0);
    acc3 = __builtin_amdgcn_mfma_f32_16x16x32_bf16(a0, b30, acc3, 0, 0, 0);
    acc3 = __builtin_amdgcn_mfma_f32_16x16x32_bf16(a1, b31, acc3, 0, 0, 0);

    float b2c0 = Wf[WF_B2 + 0 * 16 + m], b2c1 = Wf[WF_B2 + 1 * 16 + m];
    float b2c2 = Wf[WF_B2 + 2 * 16 + m], b2c3 = Wf[WF_B2 + 3 * 16 + m];
    float y0[4], y1[4], y2[4], y3[4];
    float srow[4], qrow[4];
    #pragma unroll
    for (int reg = 0; reg < 4; ++reg) {
        y0[reg] = acc0[reg] + b2c0;
        y1[reg] = acc1[reg] + b2c1;
        y2[reg] = acc2[reg] + b2c2;
        y3[reg] = acc3[reg] + b2c3;
        srow[reg] = (y0[reg] + y1[reg]) + (y2[reg] + y3[reg]);
        float qa = y0[reg] * y0[reg];
        qa = fmaf(y1[reg], y1[reg], qa);
        qa = fmaf(y2[reg], y2[reg], qa);
        qa = fmaf(y3[reg], y3[reg], qa);
        qrow[reg] = qa;
    }
    #pragma unroll
    for (int off = 1; off < 16; off <<= 1) {
        #pragma unroll
        for (int reg = 0; reg < 4; ++reg) {
            srow[reg] += __shfl_xor(srow[reg], off, 64);
            qrow[reg] += __shfl_xor(qrow[reg], off, 64);
        }
    }

    float g2c0 = Wf[WF_G2 + m],      g2c1 = Wf[WF_G2 + 16 + m];
    float g2c2 = Wf[WF_G2 + 32 + m], g2c3 = Wf[WF_G2 + 48 + m];
    float e2c0 = Wf[WF_BE2 + m],      e2c1 = Wf[WF_BE2 + 16 + m];
    float e2c2 = Wf[WF_BE2 + 32 + m], e2c3 = Wf[WF_BE2 + 48 + m];
    float w3c0 = Wf[WF_W3 + m],      w3c1 = Wf[WF_W3 + 16 + m];
    float w3c2 = Wf[WF_W3 + 32 + m], w3c3 = Wf[WF_W3 + 48 + m];
    float b3v = Wf[WF_B3];
    float o[4];
    #pragma unroll
    for (int reg = 0; reg < 4; ++reg) {
        float mu2 = srow[reg] * (1.f / 64.f);
        float rs2 = rsqrtf(qrow[reg] * (1.f / 64.f) - mu2 * mu2 + LN_EPS);
        float nm2 = -mu2 * rs2;
        float t0 = fmaxf(fmaf(fmaf(y0[reg], rs2, nm2), g2c0, e2c0), 0.f);
        float t1 = fmaxf(fmaf(fmaf(y1[reg], rs2, nm2), g2c1, e2c1), 0.f);
        float t2 = fmaxf(fmaf(fmaf(y2[reg], rs2, nm2), g2c2, e2c2), 0.f);
        float t3 = fmaxf(fmaf(fmaf(y3[reg], rs2, nm2), g2c3, e2c3), 0.f);
        o[reg] = fmaf(t0, w3c0, fmaf(t1, w3c1, fmaf(t2, w3c2, t3 * w3c3)));
    }
    #pragma unroll
    for (int off = 1; off < 16; off <<= 1) {
        #pragma unroll
        for (int reg = 0; reg < 4; ++reg) o[reg] += __shfl_xor(o[reg], off, 64);
    }
    if (m == 0) {
        long rb = b0 + quad * 4;
        if (isf32) {
            float4 v = make_float4(o[0] + b3v, o[1] + b3v, o[2] + b3v, o[3] + b3v);
            *(float4*)((float*)out + rb) = v;
        } else {
            ushort4 v;
            v.x = (unsigned short)f2bs(o[0] + b3v);
            v.y = (unsigned short)f2bs(o[1] + b3v);
            v.z = (unsigned short)f2bs(o[2] + b3v);
            v.w = (unsigned short)f2bs(o[3] + b3v);
            *(ushort4*)((bf16*)out + rb) = v;
        }
    }
}

extern "C" __attribute__((visibility("default")))
void kernel_launch(void* const* d_in, const int* in_sizes, int n_in,
                   void* d_out, int out_size, void* d_ws, size_t ws_size,
                   hipStream_t stream) {
    const void* uE   = d_in[0];
    const void* iE   = d_in[1];
    const void* uHy  = d_in[2];
    const void* iHy  = d_in[3];
    const void* W1   = d_in[4];
    const void* b1   = d_in[5];
    const void* g1   = d_in[6];
    const void* be1  = d_in[7];
    const void* W2   = d_in[8];
    const void* b2   = d_in[9];
    const void* g2   = d_in[10];
    const void* be2  = d_in[11];
    const void* W3   = d_in[12];
    const void* b3   = d_in[13];
    const void* adj_vals = d_in[14];
    const int*  adj_rows = (const int*)d_in[15];
    const int*  adj_cols = (const int*)d_in[16];
    const int*  userIdx  = (const int*)d_in[17];
    const int*  servIdx  = (const int*)d_in[18];

    char* w = (char*)d_ws;
    size_t off = 0;
    auto alloc = [&](size_t bytes) -> char* {
        char* p = w + off;
        off += (bytes + 255) & ~(size_t)255;
        return p;
    };
    float* E0   = (float*)alloc((size_t)N_CNT * D_DIM * 4);
    float* E1   = (float*)alloc((size_t)N_CNT * D_DIM * 4);
    float* P    = (float*)alloc((size_t)2 * D_DIM * H_DIM * 4);
    float* A    = (float*)alloc((size_t)N_CNT * H_DIM * 4);
    unsigned short* Ball = (unsigned short*)alloc((size_t)BALL_USHORTS * 2);
    unsigned short* Bd   = Ball;
    unsigned short* BdT  = Ball + BD_USHORTS;
    int*   flag = (int*)alloc(256);
    float* Wf   = (float*)alloc((size_t)WF_TOT * 4);
    unsigned short* Wb = (unsigned short*)alloc((size_t)4096 * 2);

    k_init<<<(BZ_QUADS + 255) / 256, 256, 0, stream>>>(uE, (uint4*)Ball, flag);
    k_pre<<<(N_CNT * D_DIM + 255) / 256, 256, 0, stream>>>(uE, iE, E0, adj_rows, adj_cols,
                                                           adj_vals, Bd, BdT, flag);
    // 3 propagation hops: E0 -> E1 -> E0 -> E1 (dense matvec, no CSR, no atomics)
    k_hop<<<899, 256, 0, stream>>>(E0, E1, Bd, BdT);
    k_hop<<<899, 256, 0, stream>>>(E1, E0, Bd, BdT);
    k_hop<<<899, 256, 0, stream>>>(E0, E1, Bd, BdT);

    k_hyperP<<<3, 256, 0, stream>>>(uHy, iHy, W1, W2, b1, g1, be1, b2, g2, be2, W3, b3,
                                    P, Wf, Wb, flag);
    k_A<<<N_CNT, H_DIM, 0, stream>>>(E1, P, Wf, A);

    int nwaves = B_CNT / 16;                          // 31250
    HyperModel_65755949301857_kernel<<<(nwaves + 3) / 4, 256, 0, stream>>>(
        A, userIdx, servIdx, Wf, Wb, d_out, flag);
}

// Round 11
// 618.350 us; speedup vs baseline: 1.4029x; 1.4029x over previous
//
#include <hip/hip_runtime.h>
#include <hip/hip_bf16.h>

#define U_CNT 339
#define S_CNT 5825
#define N_CNT 6164          // U + S
#define D_DIM 128
#define R_DIM 32
#define B_CNT 500000
#define M_EDGE 400000       // 2*NNZ (symmetrized)
#define H_DIM 64
#define LN_EPS 1e-5f

// dense adjacency (bf16), padded strides for dword-pair access
#define BD_STRIDE  5826     // Bd  rows: 340 x 5826 ushorts (row 339 stays zero = guard row)
#define BDT_STRIDE 340      // BdT rows: 5832 x 340 ushorts (rows 5825+ zero)
#define BD_USHORTS  (340 * BD_STRIDE)
#define BDT_USHORTS (5832 * BDT_STRIDE)
#define BALL_USHORTS (BD_USHORTS + BDT_USHORTS)
#define BZ_QUADS ((BALL_USHORTS * 2 + 15) / 16)

// hop kernel geometry
#define KSPLIT 8
#define UCHUNK 729          // KSPLIT*UCHUNK = 5832 >= S_CNT
#define UBLOCKS (43 * KSPLIT)   // 344: 43 row-tiles (8 u each) x 8 K-chunks
#define SBLOCKS 729             // 8 s-rows each

// fp32 weight-block offsets (elements)
#define WF_B1   4096
#define WF_G1   4160
#define WF_BE1  4224
#define WF_B2   4288
#define WF_G2   4352
#define WF_BE2  4416
#define WF_W3   4480
#define WF_B3   4544
#define WF_TOT  4545

typedef __hip_bfloat16 bf16;
typedef __attribute__((ext_vector_type(8))) short sh8;   // 8 bf16 = 4 VGPRs (MFMA A/B frag)
typedef __attribute__((ext_vector_type(4))) float f4v;   // MFMA C/D frag

__device__ __forceinline__ float b2f(bf16 x) { return __bfloat162float(x); }
__device__ __forceinline__ short f2bs(float f) {
    union { bf16 b; short s; } u;
    u.b = __float2bfloat16(f);
    return u.s;
}
__device__ __forceinline__ float bu2f(unsigned int lo16) {   // bf16 bits -> f32
    return __uint_as_float(lo16 << 16);
}

// generic float-input load: isf32 selects fp32 vs bf16 interpretation
__device__ __forceinline__ float ldf(const void* p, long i, int isf32) {
    return isf32 ? ((const float*)p)[i] : b2f(((const bf16*)p)[i]);
}

// ---------- init: zero dense adjacency + dtype detect ----------
__global__ void k_init(const void* __restrict__ uE, uint4* __restrict__ Ball,
                       int* __restrict__ flag) {
    int i = blockIdx.x * 256 + threadIdx.x;
    if (i < BZ_QUADS) Ball[i] = make_uint4(0u, 0u, 0u, 0u);
    if (blockIdx.x == 0 && threadIdx.x < 64) {
        const unsigned short* p = (const unsigned short*)uE;
        unsigned short v = p[2 * threadIdx.x];       // even bf16 element
        int e = (v >> 7) & 0xFF;                     // bf16 exponent field
        unsigned long long m = __ballot(e >= 127);   // impossible for Xavier bf16
        if (threadIdx.x == 0) flag[0] = (m != 0ull) ? 1 : 0;  // 1 => fp32 buffers
    }
}

// ---------- concat embeddings to fp32 [N,D] + dense-B scatter (NO atomics) ----------
__global__ void k_pre(const void* __restrict__ uE, const void* __restrict__ iE,
                      float* __restrict__ E, const int* __restrict__ rows,
                      const int* __restrict__ cols, const void* __restrict__ vals,
                      unsigned short* __restrict__ Bd, unsigned short* __restrict__ BdT,
                      const int* __restrict__ flag) {
    int i = blockIdx.x * 256 + threadIdx.x;
    int isf32 = flag[0];
    const int T1 = N_CNT * D_DIM;
    if (i < T1) {
        const int uTot = U_CNT * D_DIM;
        E[i] = (i < uTot) ? ldf(uE, i, isf32) : ldf(iE, i - uTot, isf32);
    }
    if (i < M_EDGE) {
        int r = rows[i], c = cols[i];
        float v = ldf(vals, i, isf32);               // bf16 inputs -> lossless
        unsigned short hv = (unsigned short)f2bs(v);
        if (r < U_CNT) Bd[r * BD_STRIDE + (c - U_CNT)] = hv;
        else           BdT[(r - U_CNT) * BDT_STRIDE + c] = hv;
    }
}

// ---------- one GCN hop: GEMM-style register tiling + split-K ----------
// R10 post-mortem: one-row-per-waveform u-side = 170 blocks x 1456 serial
// iters, 1 GB/hop L2 traffic, 219us latency-bound. Fix: 4 rows share each
// loaded e via scalar weights (register reuse), split K x8 across blocks
// (atomicAdd fp32 into memset-zeroed u-region). u-side: 344 blocks x ~729
// iters; s-side: 729 blocks x 339 iters. ~4 us/hop predicted.
__global__ void __launch_bounds__(256)
k_hop(const float* __restrict__ Ein, float* __restrict__ Eout,
      const unsigned short* __restrict__ Bd, const unsigned short* __restrict__ BdT) {
    int tid = threadIdx.x;
    int g = tid >> 7;                                 // row-group 0/1
    int d = tid & 127;
    if (blockIdx.x < UBLOCKS) {
        // ---- u-side: Eout_u[u] += Bd[u][s-chunk] . Ein_s ----
        int rt = blockIdx.x >> 3;                     // 0..42
        int ks = blockIdx.x & 7;
        int u0 = rt * 8 + g * 4;                      // rows u0..u0+3 (may exceed 338)
        int s0 = ks * UCHUNK;
        int s1 = min(s0 + UCHUNK, S_CNT);
        // clamp weight rows to the zero guard row 339
        const unsigned short* w0 = Bd + min(u0 + 0, 339) * BD_STRIDE;
        const unsigned short* w1 = Bd + min(u0 + 1, 339) * BD_STRIDE;
        const unsigned short* w2 = Bd + min(u0 + 2, 339) * BD_STRIDE;
        const unsigned short* w3 = Bd + min(u0 + 3, 339) * BD_STRIDE;
        const float* Eb = Ein + U_CNT * D_DIM + d;
        float a0 = 0, a1 = 0, a2 = 0, a3 = 0;
        #pragma unroll 4
        for (int s = s0; s < s1; ++s) {
            float e = Eb[s * D_DIM];
            a0 = fmaf(bu2f(w0[s]), e, a0);
            a1 = fmaf(bu2f(w1[s]), e, a1);
            a2 = fmaf(bu2f(w2[s]), e, a2);
            a3 = fmaf(bu2f(w3[s]), e, a3);
        }
        if (u0 + 0 < U_CNT) atomicAdd(&Eout[(u0 + 0) * D_DIM + d], a0);
        if (u0 + 1 < U_CNT) atomicAdd(&Eout[(u0 + 1) * D_DIM + d], a1);
        if (u0 + 2 < U_CNT) atomicAdd(&Eout[(u0 + 2) * D_DIM + d], a2);
        if (u0 + 3 < U_CNT) atomicAdd(&Eout[(u0 + 3) * D_DIM + d], a3);
    } else {
        // ---- s-side: Eout_s[s] = BdT[s][:] . Ein_u  (K=339, no split) ----
        int s0 = (blockIdx.x - UBLOCKS) * 8 + g * 4;  // rows s0..s0+3 (pad rows zero)
        const unsigned short* r0 = BdT + (s0 + 0) * BDT_STRIDE;
        const unsigned short* r1 = BdT + (s0 + 1) * BDT_STRIDE;
        const unsigned short* r2 = BdT + (s0 + 2) * BDT_STRIDE;
        const unsigned short* r3 = BdT + (s0 + 3) * BDT_STRIDE;
        const float* Eb = Ein + d;
        float a0 = 0, a1 = 0, a2 = 0, a3 = 0;
        #pragma unroll 4
        for (int u = 0; u < U_CNT; ++u) {
            float e = Eb[u * D_DIM];
            a0 = fmaf(bu2f(r0[u]), e, a0);
            a1 = fmaf(bu2f(r1[u]), e, a1);
            a2 = fmaf(bu2f(r2[u]), e, a2);
            a3 = fmaf(bu2f(r3[u]), e, a3);
        }
        float* Eo = Eout + (U_CNT + s0) * D_DIM + d;
        if (s0 + 0 < S_CNT) Eo[0 * D_DIM] = a0;
        if (s0 + 1 < S_CNT) Eo[1 * D_DIM] = a1;
        if (s0 + 2 < S_CNT) Eo[2 * D_DIM] = a2;
        if (s0 + 3 < S_CNT) Eo[3 * D_DIM] = a3;
    }
}

// ---------- blocks 0,1: P = Hyperᵀ(Hyper @ W1part); block 2: weight prep ----------
__global__ void k_hyperP(const void* __restrict__ uHy, const void* __restrict__ iHy,
                         const void* __restrict__ W1, const void* __restrict__ W2,
                         const void* __restrict__ b1, const void* __restrict__ g1,
                         const void* __restrict__ be1, const void* __restrict__ b2,
                         const void* __restrict__ g2, const void* __restrict__ be2,
                         const void* __restrict__ W3, const void* __restrict__ b3,
                         float* __restrict__ P, float* __restrict__ Wf,
                         unsigned short* __restrict__ Wb,
                         const int* __restrict__ flag) {
    int isf32 = flag[0];
    if (blockIdx.x == 2) {                            // weight prep
        for (int i = threadIdx.x; i < 4096; i += 256) {
            int j = i & 7, lane = (i >> 3) & 63, kh = (i >> 9) & 1, t = i >> 10;
            int k = kh * 32 + ((lane >> 4) & 3) * 8 + j;
            int n = t * 16 + (lane & 15);
            Wb[i] = (unsigned short)f2bs(ldf(W2, k * 64 + n, isf32));
        }
        for (int i = threadIdx.x; i < WF_TOT - 4096; i += 256) {
            int g = 4096 + i;
            float v;
            if      (g < WF_G1)  v = ldf(b1,  g - WF_B1,   isf32);
            else if (g < WF_BE1) v = ldf(g1,  g - WF_G1,   isf32);
            else if (g < WF_B2)  v = ldf(be1, g - WF_BE1,  isf32);
            else if (g < WF_G2)  v = ldf(b2,  g - WF_B2,   isf32);
            else if (g < WF_BE2) v = ldf(g2,  g - WF_G2,   isf32);
            else if (g < WF_W3)  v = ldf(be2, g - WF_BE2,  isf32);
            else if (g < WF_B3)  v = ldf(W3,  g - WF_W3,   isf32);
            else                 v = ldf(b3,  0,           isf32);
            Wf[g] = v;
        }
        return;
    }
    int side = blockIdx.x;                            // 0 = user, 1 = service
    const void* Hy = side ? iHy : uHy;                // [32][128]
    long wbase = (long)side * D_DIM * H_DIM;          // rows [side*128 .. +128) of W1
    __shared__ float Hs[R_DIM * D_DIM];               // 16 KB
    __shared__ float T[R_DIM * H_DIM];                // 8 KB
    for (int idx = threadIdx.x; idx < R_DIM * D_DIM; idx += 256)
        Hs[idx] = ldf(Hy, idx, isf32);
    __syncthreads();
    for (int idx = threadIdx.x; idx < R_DIM * H_DIM; idx += 256) {
        int a = idx >> 6, j = idx & 63;
        float acc = 0.f;
        for (int d = 0; d < D_DIM; ++d)
            acc = fmaf(Hs[a * D_DIM + d], ldf(W1, wbase + d * H_DIM + j, isf32), acc);
        T[idx] = acc;
    }
    __syncthreads();
    for (int idx = threadIdx.x; idx < D_DIM * H_DIM; idx += 256) {
        int d = idx >> 6, j = idx & 63;
        float acc = 0.f;
        #pragma unroll
        for (int a = 0; a < R_DIM; ++a)
            acc = fmaf(Hs[a * D_DIM + d], T[a * H_DIM + j], acc);
        P[side * D_DIM * H_DIM + idx] = acc;
    }
}

// ---------- A[r,:] = E[r,:] @ P(side) (+ b1 folded into user rows) ----------
__global__ void k_A(const float* __restrict__ E, const float* __restrict__ P,
                    const float* __restrict__ Wf, float* __restrict__ A) {
    int r = blockIdx.x;
    int j = threadIdx.x;                              // 64 threads
    const float* Pr = P + ((r < U_CNT) ? 0 : D_DIM * H_DIM);
    const float* Er = E + r * D_DIM;                  // wave-uniform -> scalar loads
    float acc = (r < U_CNT) ? Wf[WF_B1 + j] : 0.f;
    #pragma unroll 8
    for (int d = 0; d < D_DIM; ++d)
        acc = fmaf(Er[d], Pr[d * H_DIM + j], acc);
    A[r * H_DIM + j] = acc;
}

// ---------- fused MLP via MFMA: one wave per 16 batch rows, NO LDS ----------
// (R9-verified: A[m=lane&15][k=quad*8+j]; B[k=quad*8+j][n=lane&15] pre-packed;
//  C/D col=lane&15, row=quad*4+reg. LN1 via xor-16/32; LN2 via xor-1..8.)
__global__ void __launch_bounds__(256)
HyperModel_65755949301857_kernel(
      const float* __restrict__ A, const int* __restrict__ userIdx,
      const int* __restrict__ servIdx, const float* __restrict__ Wf,
      const unsigned short* __restrict__ Wb,
      void* __restrict__ out, const int* __restrict__ flag) {
    int tid = threadIdx.x;
    int wave = tid >> 6, lane = tid & 63;
    long b0 = ((long)blockIdx.x * 4 + wave) * 16;
    if (b0 >= B_CNT) return;
    int isf32 = flag[0];
    int m = lane & 15, quad = lane >> 4;

    int r = (int)b0 + m;
    int ui = userIdx[r];
    int si = servIdx[r] + U_CNT;
    const float* Aur = A + (long)ui * 64;
    const float* Asr = A + (long)si * 64;

    float4 ul0 = *(const float4*)(Aur + quad * 8);
    float4 ul1 = *(const float4*)(Aur + quad * 8 + 4);
    float4 uh0 = *(const float4*)(Aur + 32 + quad * 8);
    float4 uh1 = *(const float4*)(Aur + 32 + quad * 8 + 4);
    float4 sl0 = *(const float4*)(Asr + quad * 8);
    float4 sl1 = *(const float4*)(Asr + quad * 8 + 4);
    float4 sh0 = *(const float4*)(Asr + 32 + quad * 8);
    float4 sh1 = *(const float4*)(Asr + 32 + quad * 8 + 4);
    float zl[8], zh[8];
    zl[0] = ul0.x + sl0.x; zl[1] = ul0.y + sl0.y; zl[2] = ul0.z + sl0.z; zl[3] = ul0.w + sl0.w;
    zl[4] = ul1.x + sl1.x; zl[5] = ul1.y + sl1.y; zl[6] = ul1.z + sl1.z; zl[7] = ul1.w + sl1.w;
    zh[0] = uh0.x + sh0.x; zh[1] = uh0.y + sh0.y; zh[2] = uh0.z + sh0.z; zh[3] = uh0.w + sh0.w;
    zh[4] = uh1.x + sh1.x; zh[5] = uh1.y + sh1.y; zh[6] = uh1.z + sh1.z; zh[7] = uh1.w + sh1.w;

    float s = 0.f, q = 0.f;
    #pragma unroll
    for (int j = 0; j < 8; ++j) {
        s += zl[j] + zh[j];
        q = fmaf(zl[j], zl[j], q);
        q = fmaf(zh[j], zh[j], q);
    }
    s += __shfl_xor(s, 16, 64); s += __shfl_xor(s, 32, 64);
    q += __shfl_xor(q, 16, 64); q += __shfl_xor(q, 32, 64);
    float mu = s * (1.f / 64.f);
    float rs = rsqrtf(q * (1.f / 64.f) - mu * mu + LN_EPS);
    float nm = -mu * rs;

    const float* G1l = Wf + WF_G1 + quad * 8;
    const float* BE1l = Wf + WF_BE1 + quad * 8;
    sh8 a0, a1;
    #pragma unroll
    for (int j = 0; j < 8; ++j) {
        float h0 = fmaxf(fmaf(fmaf(zl[j], rs, nm), G1l[j],      BE1l[j]),      0.f);
        float h1 = fmaxf(fmaf(fmaf(zh[j], rs, nm), G1l[32 + j], BE1l[32 + j]), 0.f);
        a0[j] = f2bs(h0);
        a1[j] = f2bs(h1);
    }

    const sh8* Bp = (const sh8*)Wb;
    sh8 b00 = Bp[0 * 64 + lane], b01 = Bp[1 * 64 + lane];
    sh8 b10 = Bp[2 * 64 + lane], b11 = Bp[3 * 64 + lane];
    sh8 b20 = Bp[4 * 64 + lane], b21 = Bp[5 * 64 + lane];
    sh8 b30 = Bp[6 * 64 + lane], b31 = Bp[7 * 64 + lane];
    f4v acc0 = {0.f, 0.f, 0.f, 0.f}, acc1 = acc0, acc2 = acc0, acc3 = acc0;
    acc0 = __builtin_amdgcn_mfma_f32_16x16x32_bf16(a0, b00, acc0, 0, 0, 0);
    acc0 = __builtin_amdgcn_mfma_f32_16x16x32_bf16(a1, b01, acc0, 0, 0, 0);
    acc1 = __builtin_amdgcn_mfma_f32_16x16x32_bf16(a0, b10, acc1, 0, 0, 0);
    acc1 = __builtin_amdgcn_mfma_f32_16x16x32_bf16(a1, b11, acc1, 0, 0, 0);
    acc2 = __builtin_amdgcn_mfma_f32_16x16x32_bf16(a0, b20, acc2, 0, 0, 0);
    acc2 = __builtin_amdgcn_mfma_f32_16x16x32_bf16(a1, b21, acc2, 0, 0, 0);
    acc3 = __builtin_amdgcn_mfma_f32_16x16x32_bf16(a0, b30, acc3, 0, 0, 0);
    acc3 = __builtin_amdgcn_mfma_f32_16x16x32_bf16(a1, b31, acc3, 0, 0, 0);

    float b2c0 = Wf[WF_B2 + 0 * 16 + m], b2c1 = Wf[WF_B2 + 1 * 16 + m];
    float b2c2 = Wf[WF_B2 + 2 * 16 + m], b2c3 = Wf[WF_B2 + 3 * 16 + m];
    float y0[4], y1[4], y2[4], y3[4];
    float srow[4], qrow[4];
    #pragma unroll
    for (int reg = 0; reg < 4; ++reg) {
        y0[reg] = acc0[reg] + b2c0;
        y1[reg] = acc1[reg] + b2c1;
        y2[reg] = acc2[reg] + b2c2;
        y3[reg] = acc3[reg] + b2c3;
        srow[reg] = (y0[reg] + y1[reg]) + (y2[reg] + y3[reg]);
        float qa = y0[reg] * y0[reg];
        qa = fmaf(y1[reg], y1[reg], qa);
        qa = fmaf(y2[reg], y2[reg], qa);
        qa = fmaf(y3[reg], y3[reg], qa);
        qrow[reg] = qa;
    }
    #pragma unroll
    for (int off = 1; off < 16; off <<= 1) {
        #pragma unroll
        for (int reg = 0; reg < 4; ++reg) {
            srow[reg] += __shfl_xor(srow[reg], off, 64);
            qrow[reg] += __shfl_xor(qrow[reg], off, 64);
        }
    }

    float g2c0 = Wf[WF_G2 + m],      g2c1 = Wf[WF_G2 + 16 + m];
    float g2c2 = Wf[WF_G2 + 32 + m], g2c3 = Wf[WF_G2 + 48 + m];
    float e2c0 = Wf[WF_BE2 + m],      e2c1 = Wf[WF_BE2 + 16 + m];
    float e2c2 = Wf[WF_BE2 + 32 + m], e2c3 = Wf[WF_BE2 + 48 + m];
    float w3c0 = Wf[WF_W3 + m],      w3c1 = Wf[WF_W3 + 16 + m];
    float w3c2 = Wf[WF_W3 + 32 + m], w3c3 = Wf[WF_W3 + 48 + m];
    float b3v = Wf[WF_B3];
    float o[4];
    #pragma unroll
    for (int reg = 0; reg < 4; ++reg) {
        float mu2 = srow[reg] * (1.f / 64.f);
        float rs2 = rsqrtf(qrow[reg] * (1.f / 64.f) - mu2 * mu2 + LN_EPS);
        float nm2 = -mu2 * rs2;
        float t0 = fmaxf(fmaf(fmaf(y0[reg], rs2, nm2), g2c0, e2c0), 0.f);
        float t1 = fmaxf(fmaf(fmaf(y1[reg], rs2, nm2), g2c1, e2c1), 0.f);
        float t2 = fmaxf(fmaf(fmaf(y2[reg], rs2, nm2), g2c2, e2c2), 0.f);
        float t3 = fmaxf(fmaf(fmaf(y3[reg], rs2, nm2), g2c3, e2c3), 0.f);
        o[reg] = fmaf(t0, w3c0, fmaf(t1, w3c1, fmaf(t2, w3c2, t3 * w3c3)));
    }
    #pragma unroll
    for (int off = 1; off < 16; off <<= 1) {
        #pragma unroll
        for (int reg = 0; reg < 4; ++reg) o[reg] += __shfl_xor(o[reg], off, 64);
    }
    if (m == 0) {
        long rb = b0 + quad * 4;
        if (isf32) {
            float4 v = make_float4(o[0] + b3v, o[1] + b3v, o[2] + b3v, o[3] + b3v);
            *(float4*)((float*)out + rb) = v;
        } else {
            ushort4 v;
            v.x = (unsigned short)f2bs(o[0] + b3v);
            v.y = (unsigned short)f2bs(o[1] + b3v);
            v.z = (unsigned short)f2bs(o[2] + b3v);
            v.w = (unsigned short)f2bs(o[3] + b3v);
            *(ushort4*)((bf16*)out + rb) = v;
        }
    }
}

extern "C" __attribute__((visibility("default")))
void kernel_launch(void* const* d_in, const int* in_sizes, int n_in,
                   void* d_out, int out_size, void* d_ws, size_t ws_size,
                   hipStream_t stream) {
    const void* uE   = d_in[0];
    const void* iE   = d_in[1];
    const void* uHy  = d_in[2];
    const void* iHy  = d_in[3];
    const void* W1   = d_in[4];
    const void* b1   = d_in[5];
    const void* g1   = d_in[6];
    const void* be1  = d_in[7];
    const void* W2   = d_in[8];
    const void* b2   = d_in[9];
    const void* g2   = d_in[10];
    const void* be2  = d_in[11];
    const void* W3   = d_in[12];
    const void* b3   = d_in[13];
    const void* adj_vals = d_in[14];
    const int*  adj_rows = (const int*)d_in[15];
    const int*  adj_cols = (const int*)d_in[16];
    const int*  userIdx  = (const int*)d_in[17];
    const int*  servIdx  = (const int*)d_in[18];

    char* w = (char*)d_ws;
    size_t off = 0;
    auto alloc = [&](size_t bytes) -> char* {
        char* p = w + off;
        off += (bytes + 255) & ~(size_t)255;
        return p;
    };
    float* E0   = (float*)alloc((size_t)N_CNT * D_DIM * 4);
    float* E1   = (float*)alloc((size_t)N_CNT * D_DIM * 4);
    float* P    = (float*)alloc((size_t)2 * D_DIM * H_DIM * 4);
    float* A    = (float*)alloc((size_t)N_CNT * H_DIM * 4);
    unsigned short* Ball = (unsigned short*)alloc((size_t)BALL_USHORTS * 2);
    unsigned short* Bd   = Ball;
    unsigned short* BdT  = Ball + BD_USHORTS;
    int*   flag = (int*)alloc(256);
    float* Wf   = (float*)alloc((size_t)WF_TOT * 4);
    unsigned short* Wb = (unsigned short*)alloc((size_t)4096 * 2);

    const size_t uBytes = (size_t)U_CNT * D_DIM * 4;  // 173.5 KB u-region

    k_init<<<(BZ_QUADS + 255) / 256, 256, 0, stream>>>(uE, (uint4*)Ball, flag);
    k_pre<<<(N_CNT * D_DIM + 255) / 256, 256, 0, stream>>>(uE, iE, E0, adj_rows, adj_cols,
                                                           adj_vals, Bd, BdT, flag);
    // 3 hops; u-region of the destination must be zero for split-K atomics
    hipMemsetAsync(E1, 0, uBytes, stream);
    k_hop<<<UBLOCKS + SBLOCKS, 256, 0, stream>>>(E0, E1, Bd, BdT);
    hipMemsetAsync(E0, 0, uBytes, stream);
    k_hop<<<UBLOCKS + SBLOCKS, 256, 0, stream>>>(E1, E0, Bd, BdT);
    hipMemsetAsync(E1, 0, uBytes, stream);
    k_hop<<<UBLOCKS + SBLOCKS, 256, 0, stream>>>(E0, E1, Bd, BdT);

    k_hyperP<<<3, 256, 0, stream>>>(uHy, iHy, W1, W2, b1, g1, be1, b2, g2, be2, W3, b3,
                                    P, Wf, Wb, flag);
    k_A<<<N_CNT, H_DIM, 0, stream>>>(E1, P, Wf, A);

    int nwaves = B_CNT / 16;                          // 31250
    HyperModel_65755949301857_kernel<<<(nwaves + 3) / 4, 256, 0, stream>>>(
        A, userIdx, servIdx, Wf, Wb, d_out, flag);
}

// Round 12
// 403.400 us; speedup vs baseline: 2.1505x; 1.5328x over previous
//
#include <hip/hip_runtime.h>
#include <hip/hip_bf16.h>

#define U_CNT 339
#define S_CNT 5825
#define N_CNT 6164          // U + S
#define D_DIM 128
#define R_DIM 32
#define B_CNT 500000
#define M_EDGE 400000       // 2*NNZ (symmetrized)
#define H_DIM 64
#define LN_EPS 1e-5f

// ---- transposed E layout: Et[d][col], col(u)=u (0..351 pad), col(s)=352+s ----
#define NPAD 6208           // 352 (u pad) + 5856 (s pad)
#define COL_S0 352
#define ET_U16 (128 * NPAD) // 794,624 ushorts per plane

// ---- adjacency packed as MFMA B-fragments (bf16) ----
#define KT_U 11             // u as K: 352/32
#define KT_S 183            // s as K: 5856/32
#define NT_S 365            // s as N: 5840/16
#define NT_U 22             // u as N: 352/16
#define PKS_U16 (KT_U * NT_S * 512)   // B[k=u][n=s], 2,055,680
#define PKU_U16 (KT_S * NT_U * 512)   // B[k=s][n=u], 2,061,312

#define S_WAVES (8 * NT_S)  // 2920
#define U_WAVES (8 * NT_U)  // 176
#define HOP_BLOCKS ((S_WAVES + U_WAVES) / 4)   // 774 exactly

// fp32 weight-block offsets (elements)
#define WF_B1   4096
#define WF_G1   4160
#define WF_BE1  4224
#define WF_B2   4288
#define WF_G2   4352
#define WF_BE2  4416
#define WF_W3   4480
#define WF_B3   4544
#define WF_TOT  4545

typedef __hip_bfloat16 bf16;
typedef __attribute__((ext_vector_type(8))) short sh8;   // 8 bf16 (MFMA A/B frag)
typedef __attribute__((ext_vector_type(4))) float f4v;   // MFMA C/D frag

__device__ __forceinline__ float b2f(bf16 x) { return __bfloat162float(x); }
__device__ __forceinline__ unsigned short f2bs(float f) {
    union { bf16 b; unsigned short s; } u;
    u.b = __float2bfloat16(f);
    return u.s;
}
__device__ __forceinline__ float bu2f(unsigned int lo16) {   // bf16 bits -> f32
    return __uint_as_float(lo16 << 16);
}
__device__ __forceinline__ float ldf(const void* p, long i, int isf32) {
    return isf32 ? ((const float*)p)[i] : b2f(((const bf16*)p)[i]);
}

// ---------- init: zero Et planes + packed adjacency; dtype detect ----------
__global__ void k_init(const void* __restrict__ uE, uint4* __restrict__ zbase,
                       int n_quads, int* __restrict__ flag) {
    int i = blockIdx.x * 256 + threadIdx.x;
    if (i < n_quads) zbase[i] = make_uint4(0u, 0u, 0u, 0u);
    if (blockIdx.x == 0 && threadIdx.x < 64) {
        const unsigned short* p = (const unsigned short*)uE;
        unsigned short v = p[2 * threadIdx.x];
        int e = (v >> 7) & 0xFF;
        unsigned long long m = __ballot(e >= 127);
        if (threadIdx.x == 0) flag[0] = (m != 0ull) ? 1 : 0;  // 1 => fp32 buffers
    }
}

// ---------- pre: E -> transposed hi/lo planes (LDS transpose) + edge pack ----------
__global__ void __launch_bounds__(256)
k_pre(const void* __restrict__ uE, const void* __restrict__ iE,
      unsigned short* __restrict__ EtHi, unsigned short* __restrict__ EtLo,
      const int* __restrict__ rows, const int* __restrict__ cols,
      const void* __restrict__ vals,
      unsigned short* __restrict__ PkS, unsigned short* __restrict__ PkU,
      const int* __restrict__ flag) {
    __shared__ float ls[32 * 129];                    // padded: conflict-free
    int tid = threadIdx.x;
    int isf32 = flag[0];
    if (blockIdx.x < 193) {                           // node-transpose role
        int ng0 = blockIdx.x * 32;
        int nl = tid >> 3, dbase = (tid & 7) * 16;
        int node = ng0 + nl;
        #pragma unroll
        for (int i = 0; i < 16; ++i) {
            int d = dbase + i;
            float v = 0.f;
            if (node < N_CNT) {
                v = (node < U_CNT) ? ldf(uE, (long)node * D_DIM + d, isf32)
                                   : ldf(iE, (long)(node - U_CNT) * D_DIM + d, isf32);
            }
            ls[nl * 129 + d] = v;
        }
        __syncthreads();
        int nl2 = tid & 31;
        int node2 = ng0 + nl2;
        int c = (node2 < U_CNT) ? node2 : COL_S0 + (node2 - U_CNT);
        #pragma unroll
        for (int i = 0; i < 16; ++i) {
            int d = (tid >> 5) * 16 + i;
            float v = ls[nl2 * 129 + d];
            unsigned short hi = f2bs(v);
            unsigned short lo = f2bs(v - bu2f(hi));
            EtHi[d * NPAD + c] = hi;
            EtLo[d * NPAD + c] = lo;
        }
    }
    // edge packing role (all blocks): only r < U edges carry both orientations
    int e = blockIdx.x * 256 + tid;
    if (e < M_EDGE) {
        int r = rows[e];
        if (r < U_CNT) {
            int u = r, s = cols[e] - U_CNT;
            unsigned short w = f2bs(ldf(vals, e, isf32));
            // PkS: B[k=u][n=s]
            int kt = u >> 5, kq = (u >> 3) & 3, j = u & 7;
            int nt = s >> 4, nn = s & 15;
            PkS[((kt * NT_S + nt) * 64 + kq * 16 + nn) * 8 + j] = w;
            // PkU: B[k=s][n=u]
            int kt2 = s >> 5, kq2 = (s >> 3) & 3, j2 = s & 7;
            int nt2 = u >> 4, nn2 = u & 15;
            PkU[((kt2 * NT_U + nt2) * 64 + kq2 * 16 + nn2) * 8 + j2] = w;
        }
    }
}

// ---------- one GCN hop: MFMA GEMM, split-precision E (hi+lo bf16) ----------
// Eout^T = Et_in @ B  per side. A[m=lane&15][k=quad*8+j] from Et rows (16B
// contiguous); B pre-packed fragments; C/D col=lane&15, row=quad*4+reg
// (all layouts R9-verified). acc += A_hi*B + A_lo*B keeps fp32-equivalent
// precision (lo = bf16 residual, error ~2^-17/hop).
__global__ void __launch_bounds__(256)
k_hop(const unsigned short* __restrict__ EinHi, const unsigned short* __restrict__ EinLo,
      unsigned short* __restrict__ EoutHi, unsigned short* __restrict__ EoutLo,
      const unsigned short* __restrict__ PkS, const unsigned short* __restrict__ PkU) {
    int wid = blockIdx.x * 4 + (threadIdx.x >> 6);
    int lane = threadIdx.x & 63;
    int am = lane & 15, aq = lane >> 4;
    f4v acc = {0.f, 0.f, 0.f, 0.f};
    int outcol, d0;
    if (wid < S_WAVES) {
        int mt = wid / NT_S, nt = wid % NT_S;
        d0 = mt * 16;
        const unsigned short* arowH = EinHi + (size_t)(d0 + am) * NPAD;
        const unsigned short* arowL = EinLo + (size_t)(d0 + am) * NPAD;
        const sh8* Bp = (const sh8*)PkS;
        #pragma unroll
        for (int kt = 0; kt < KT_U; ++kt) {
            sh8 ah = *(const sh8*)(arowH + kt * 32 + aq * 8);
            sh8 al = *(const sh8*)(arowL + kt * 32 + aq * 8);
            sh8 bb = Bp[(kt * NT_S + nt) * 64 + lane];
            acc = __builtin_amdgcn_mfma_f32_16x16x32_bf16(ah, bb, acc, 0, 0, 0);
            acc = __builtin_amdgcn_mfma_f32_16x16x32_bf16(al, bb, acc, 0, 0, 0);
        }
        outcol = COL_S0 + nt * 16 + am;
    } else {
        int wid2 = wid - S_WAVES;
        int mt = wid2 / NT_U, nt = wid2 % NT_U;
        d0 = mt * 16;
        const unsigned short* arowH = EinHi + (size_t)(d0 + am) * NPAD + COL_S0;
        const unsigned short* arowL = EinLo + (size_t)(d0 + am) * NPAD + COL_S0;
        const sh8* Bp = (const sh8*)PkU;
        #pragma unroll 4
        for (int kt = 0; kt < KT_S; ++kt) {
            sh8 ah = *(const sh8*)(arowH + kt * 32 + aq * 8);
            sh8 al = *(const sh8*)(arowL + kt * 32 + aq * 8);
            sh8 bb = Bp[(kt * NT_U + nt) * 64 + lane];
            acc = __builtin_amdgcn_mfma_f32_16x16x32_bf16(ah, bb, acc, 0, 0, 0);
            acc = __builtin_amdgcn_mfma_f32_16x16x32_bf16(al, bb, acc, 0, 0, 0);
        }
        outcol = nt * 16 + am;
    }
    #pragma unroll
    for (int reg = 0; reg < 4; ++reg) {
        int d = d0 + aq * 4 + reg;
        float v = acc[reg];
        unsigned short hi = f2bs(v);
        unsigned short lo = f2bs(v - bu2f(hi));
        EoutHi[(size_t)d * NPAD + outcol] = hi;
        EoutLo[(size_t)d * NPAD + outcol] = lo;
    }
}

// ---------- blocks 0,1: P = Hyperᵀ(Hyper @ W1part); block 2: weight prep ----------
__global__ void k_hyperP(const void* __restrict__ uHy, const void* __restrict__ iHy,
                         const void* __restrict__ W1, const void* __restrict__ W2,
                         const void* __restrict__ b1, const void* __restrict__ g1,
                         const void* __restrict__ be1, const void* __restrict__ b2,
                         const void* __restrict__ g2, const void* __restrict__ be2,
                         const void* __restrict__ W3, const void* __restrict__ b3,
                         float* __restrict__ P, float* __restrict__ Wf,
                         unsigned short* __restrict__ Wb,
                         const int* __restrict__ flag) {
    int isf32 = flag[0];
    if (blockIdx.x == 2) {                            // weight prep
        for (int i = threadIdx.x; i < 4096; i += 256) {
            int j = i & 7, lane = (i >> 3) & 63, kh = (i >> 9) & 1, t = i >> 10;
            int k = kh * 32 + ((lane >> 4) & 3) * 8 + j;
            int n = t * 16 + (lane & 15);
            Wb[i] = f2bs(ldf(W2, k * 64 + n, isf32));
        }
        for (int i = threadIdx.x; i < WF_TOT - 4096; i += 256) {
            int g = 4096 + i;
            float v;
            if      (g < WF_G1)  v = ldf(b1,  g - WF_B1,   isf32);
            else if (g < WF_BE1) v = ldf(g1,  g - WF_G1,   isf32);
            else if (g < WF_B2)  v = ldf(be1, g - WF_BE1,  isf32);
            else if (g < WF_G2)  v = ldf(b2,  g - WF_B2,   isf32);
            else if (g < WF_BE2) v = ldf(g2,  g - WF_G2,   isf32);
            else if (g < WF_W3)  v = ldf(be2, g - WF_BE2,  isf32);
            else if (g < WF_B3)  v = ldf(W3,  g - WF_W3,   isf32);
            else                 v = ldf(b3,  0,           isf32);
            Wf[g] = v;
        }
        return;
    }
    int side = blockIdx.x;                            // 0 = user, 1 = service
    const void* Hy = side ? iHy : uHy;                // [32][128]
    long wbase = (long)side * D_DIM * H_DIM;
    __shared__ float Hs[R_DIM * D_DIM];
    __shared__ float T[R_DIM * H_DIM];
    for (int idx = threadIdx.x; idx < R_DIM * D_DIM; idx += 256)
        Hs[idx] = ldf(Hy, idx, isf32);
    __syncthreads();
    for (int idx = threadIdx.x; idx < R_DIM * H_DIM; idx += 256) {
        int a = idx >> 6, j = idx & 63;
        float acc = 0.f;
        for (int d = 0; d < D_DIM; ++d)
            acc = fmaf(Hs[a * D_DIM + d], ldf(W1, wbase + d * H_DIM + j, isf32), acc);
        T[idx] = acc;
    }
    __syncthreads();
    for (int idx = threadIdx.x; idx < D_DIM * H_DIM; idx += 256) {
        int d = idx >> 6, j = idx & 63;
        float acc = 0.f;
        #pragma unroll
        for (int a = 0; a < R_DIM; ++a)
            acc = fmaf(Hs[a * D_DIM + d], T[a * H_DIM + j], acc);
        P[side * D_DIM * H_DIM + idx] = acc;
    }
}

// ---------- A[r,:] = E[r,:] @ P(side) (+ b1), reading transposed hi/lo E ----------
__global__ void k_A(const unsigned short* __restrict__ EtHi,
                    const unsigned short* __restrict__ EtLo,
                    const float* __restrict__ P, const float* __restrict__ Wf,
                    float* __restrict__ A) {
    int r = blockIdx.x;
    int j = threadIdx.x;                              // 64 threads
    int c = (r < U_CNT) ? r : COL_S0 + (r - U_CNT);
    const float* Pr = P + ((r < U_CNT) ? 0 : D_DIM * H_DIM);
    float acc = (r < U_CNT) ? Wf[WF_B1 + j] : 0.f;
    #pragma unroll 8
    for (int d = 0; d < D_DIM; ++d) {
        float e = bu2f(EtHi[(size_t)d * NPAD + c]) + bu2f(EtLo[(size_t)d * NPAD + c]);
        acc = fmaf(e, Pr[d * H_DIM + j], acc);
    }
    A[r * H_DIM + j] = acc;
}

// ---------- fused MLP via MFMA (R9-verified, unchanged) ----------
__global__ void __launch_bounds__(256)
HyperModel_65755949301857_kernel(
      const float* __restrict__ A, const int* __restrict__ userIdx,
      const int* __restrict__ servIdx, const float* __restrict__ Wf,
      const unsigned short* __restrict__ Wb,
      void* __restrict__ out, const int* __restrict__ flag) {
    int tid = threadIdx.x;
    int wave = tid >> 6, lane = tid & 63;
    long b0 = ((long)blockIdx.x * 4 + wave) * 16;
    if (b0 >= B_CNT) return;
    int isf32 = flag[0];
    int m = lane & 15, quad = lane >> 4;

    int r = (int)b0 + m;
    int ui = userIdx[r];
    int si = servIdx[r] + U_CNT;
    const float* Aur = A + (long)ui * 64;
    const float* Asr = A + (long)si * 64;

    float4 ul0 = *(const float4*)(Aur + quad * 8);
    float4 ul1 = *(const float4*)(Aur + quad * 8 + 4);
    float4 uh0 = *(const float4*)(Aur + 32 + quad * 8);
    float4 uh1 = *(const float4*)(Aur + 32 + quad * 8 + 4);
    float4 sl0 = *(const float4*)(Asr + quad * 8);
    float4 sl1 = *(const float4*)(Asr + quad * 8 + 4);
    float4 sh0 = *(const float4*)(Asr + 32 + quad * 8);
    float4 sh1 = *(const float4*)(Asr + 32 + quad * 8 + 4);
    float zl[8], zh[8];
    zl[0] = ul0.x + sl0.x; zl[1] = ul0.y + sl0.y; zl[2] = ul0.z + sl0.z; zl[3] = ul0.w + sl0.w;
    zl[4] = ul1.x + sl1.x; zl[5] = ul1.y + sl1.y; zl[6] = ul1.z + sl1.z; zl[7] = ul1.w + sl1.w;
    zh[0] = uh0.x + sh0.x; zh[1] = uh0.y + sh0.y; zh[2] = uh0.z + sh0.z; zh[3] = uh0.w + sh0.w;
    zh[4] = uh1.x + sh1.x; zh[5] = uh1.y + sh1.y; zh[6] = uh1.z + sh1.z; zh[7] = uh1.w + sh1.w;

    float s = 0.f, q = 0.f;
    #pragma unroll
    for (int j = 0; j < 8; ++j) {
        s += zl[j] + zh[j];
        q = fmaf(zl[j], zl[j], q);
        q = fmaf(zh[j], zh[j], q);
    }
    s += __shfl_xor(s, 16, 64); s += __shfl_xor(s, 32, 64);
    q += __shfl_xor(q, 16, 64); q += __shfl_xor(q, 32, 64);
    float mu = s * (1.f / 64.f);
    float rs = rsqrtf(q * (1.f / 64.f) - mu * mu + LN_EPS);
    float nm = -mu * rs;

    const float* G1l = Wf + WF_G1 + quad * 8;
    const float* BE1l = Wf + WF_BE1 + quad * 8;
    sh8 a0, a1;
    #pragma unroll
    for (int j = 0; j < 8; ++j) {
        float h0 = fmaxf(fmaf(fmaf(zl[j], rs, nm), G1l[j],      BE1l[j]),      0.f);
        float h1 = fmaxf(fmaf(fmaf(zh[j], rs, nm), G1l[32 + j], BE1l[32 + j]), 0.f);
        a0[j] = (short)f2bs(h0);
        a1[j] = (short)f2bs(h1);
    }

    const sh8* Bp = (const sh8*)Wb;
    sh8 b00 = Bp[0 * 64 + lane], b01 = Bp[1 * 64 + lane];
    sh8 b10 = Bp[2 * 64 + lane], b11 = Bp[3 * 64 + lane];
    sh8 b20 = Bp[4 * 64 + lane], b21 = Bp[5 * 64 + lane];
    sh8 b30 = Bp[6 * 64 + lane], b31 = Bp[7 * 64 + lane];
    f4v acc0 = {0.f, 0.f, 0.f, 0.f}, acc1 = acc0, acc2 = acc0, acc3 = acc0;
    acc0 = __builtin_amdgcn_mfma_f32_16x16x32_bf16(a0, b00, acc0, 0, 0, 0);
    acc0 = __builtin_amdgcn_mfma_f32_16x16x32_bf16(a1, b01, acc0, 0, 0, 0);
    acc1 = __builtin_amdgcn_mfma_f32_16x16x32_bf16(a0, b10, acc1, 0, 0, 0);
    acc1 = __builtin_amdgcn_mfma_f32_16x16x32_bf16(a1, b11, acc1, 0, 0, 0);
    acc2 = __builtin_amdgcn_mfma_f32_16x16x32_bf16(a0, b20, acc2, 0, 0, 0);
    acc2 = __builtin_amdgcn_mfma_f32_16x16x32_bf16(a1, b21, acc2, 0, 0, 0);
    acc3 = __builtin_amdgcn_mfma_f32_16x16x32_bf16(a0, b30, acc3, 0, 0, 0);
    acc3 = __builtin_amdgcn_mfma_f32_16x16x32_bf16(a1, b31, acc3, 0, 0, 0);

    float b2c0 = Wf[WF_B2 + 0 * 16 + m], b2c1 = Wf[WF_B2 + 1 * 16 + m];
    float b2c2 = Wf[WF_B2 + 2 * 16 + m], b2c3 = Wf[WF_B2 + 3 * 16 + m];
    float y0[4], y1[4], y2[4], y3[4];
    float srow[4], qrow[4];
    #pragma unroll
    for (int reg = 0; reg < 4; ++reg) {
        y0[reg] = acc0[reg] + b2c0;
        y1[reg] = acc1[reg] + b2c1;
        y2[reg] = acc2[reg] + b2c2;
        y3[reg] = acc3[reg] + b2c3;
        srow[reg] = (y0[reg] + y1[reg]) + (y2[reg] + y3[reg]);
        float qa = y0[reg] * y0[reg];
        qa = fmaf(y1[reg], y1[reg], qa);
        qa = fmaf(y2[reg], y2[reg], qa);
        qa = fmaf(y3[reg], y3[reg], qa);
        qrow[reg] = qa;
    }
    #pragma unroll
    for (int off = 1; off < 16; off <<= 1) {
        #pragma unroll
        for (int reg = 0; reg < 4; ++reg) {
            srow[reg] += __shfl_xor(srow[reg], off, 64);
            qrow[reg] += __shfl_xor(qrow[reg], off, 64);
        }
    }

    float g2c0 = Wf[WF_G2 + m],      g2c1 = Wf[WF_G2 + 16 + m];
    float g2c2 = Wf[WF_G2 + 32 + m], g2c3 = Wf[WF_G2 + 48 + m];
    float e2c0 = Wf[WF_BE2 + m],      e2c1 = Wf[WF_BE2 + 16 + m];
    float e2c2 = Wf[WF_BE2 + 32 + m], e2c3 = Wf[WF_BE2 + 48 + m];
    float w3c0 = Wf[WF_W3 + m],      w3c1 = Wf[WF_W3 + 16 + m];
    float w3c2 = Wf[WF_W3 + 32 + m], w3c3 = Wf[WF_W3 + 48 + m];
    float b3v = Wf[WF_B3];
    float o[4];
    #pragma unroll
    for (int reg = 0; reg < 4; ++reg) {
        float mu2 = srow[reg] * (1.f / 64.f);
        float rs2 = rsqrtf(qrow[reg] * (1.f / 64.f) - mu2 * mu2 + LN_EPS);
        float nm2 = -mu2 * rs2;
        float t0 = fmaxf(fmaf(fmaf(y0[reg], rs2, nm2), g2c0, e2c0), 0.f);
        float t1 = fmaxf(fmaf(fmaf(y1[reg], rs2, nm2), g2c1, e2c1), 0.f);
        float t2 = fmaxf(fmaf(fmaf(y2[reg], rs2, nm2), g2c2, e2c2), 0.f);
        float t3 = fmaxf(fmaf(fmaf(y3[reg], rs2, nm2), g2c3, e2c3), 0.f);
        o[reg] = fmaf(t0, w3c0, fmaf(t1, w3c1, fmaf(t2, w3c2, t3 * w3c3)));
    }
    #pragma unroll
    for (int off = 1; off < 16; off <<= 1) {
        #pragma unroll
        for (int reg = 0; reg < 4; ++reg) o[reg] += __shfl_xor(o[reg], off, 64);
    }
    if (m == 0) {
        long rb = b0 + quad * 4;
        if (isf32) {
            float4 v = make_float4(o[0] + b3v, o[1] + b3v, o[2] + b3v, o[3] + b3v);
            *(float4*)((float*)out + rb) = v;
        } else {
            ushort4 v;
            v.x = f2bs(o[0] + b3v);
            v.y = f2bs(o[1] + b3v);
            v.z = f2bs(o[2] + b3v);
            v.w = f2bs(o[3] + b3v);
            *(ushort4*)((bf16*)out + rb) = v;
        }
    }
}

extern "C" __attribute__((visibility("default")))
void kernel_launch(void* const* d_in, const int* in_sizes, int n_in,
                   void* d_out, int out_size, void* d_ws, size_t ws_size,
                   hipStream_t stream) {
    const void* uE   = d_in[0];
    const void* iE   = d_in[1];
    const void* uHy  = d_in[2];
    const void* iHy  = d_in[3];
    const void* W1   = d_in[4];
    const void* b1   = d_in[5];
    const void* g1   = d_in[6];
    const void* be1  = d_in[7];
    const void* W2   = d_in[8];
    const void* b2   = d_in[9];
    const void* g2   = d_in[10];
    const void* be2  = d_in[11];
    const void* W3   = d_in[12];
    const void* b3   = d_in[13];
    const void* adj_vals = d_in[14];
    const int*  adj_rows = (const int*)d_in[15];
    const int*  adj_cols = (const int*)d_in[16];
    const int*  userIdx  = (const int*)d_in[17];
    const int*  servIdx  = (const int*)d_in[18];

    char* w = (char*)d_ws;
    size_t off = 0;
    auto alloc = [&](size_t bytes) -> char* {
        char* p = w + off;
        off += (bytes + 255) & ~(size_t)255;
        return p;
    };
    // contiguous zero region: 4 Et planes + both packed adjacencies
    char* zstart = w;
    unsigned short* E0Hi = (unsigned short*)alloc((size_t)ET_U16 * 2);
    unsigned short* E0Lo = (unsigned short*)alloc((size_t)ET_U16 * 2);
    unsigned short* E1Hi = (unsigned short*)alloc((size_t)ET_U16 * 2);
    unsigned short* E1Lo = (unsigned short*)alloc((size_t)ET_U16 * 2);
    unsigned short* PkS  = (unsigned short*)alloc((size_t)PKS_U16 * 2);
    unsigned short* PkU  = (unsigned short*)alloc((size_t)PKU_U16 * 2);
    size_t zbytes = (size_t)(w + off - zstart);
    int n_quads = (int)(zbytes / 16);                 // all pieces 256-aligned

    float* P    = (float*)alloc((size_t)2 * D_DIM * H_DIM * 4);
    float* A    = (float*)alloc((size_t)N_CNT * H_DIM * 4);
    int*   flag = (int*)alloc(256);
    float* Wf   = (float*)alloc((size_t)WF_TOT * 4);
    unsigned short* Wb = (unsigned short*)alloc((size_t)4096 * 2);

    k_init<<<(n_quads + 255) / 256, 256, 0, stream>>>(uE, (uint4*)zstart, n_quads, flag);
    k_pre<<<(M_EDGE + 255) / 256, 256, 0, stream>>>(uE, iE, E0Hi, E0Lo,
                                                    adj_rows, adj_cols, adj_vals,
                                                    PkS, PkU, flag);
    // 3 hops: E0 -> E1 -> E0 -> E1 (MFMA GEMM, split-precision)
    k_hop<<<HOP_BLOCKS, 256, 0, stream>>>(E0Hi, E0Lo, E1Hi, E1Lo, PkS, PkU);
    k_hop<<<HOP_BLOCKS, 256, 0, stream>>>(E1Hi, E1Lo, E0Hi, E0Lo, PkS, PkU);
    k_hop<<<HOP_BLOCKS, 256, 0, stream>>>(E0Hi, E0Lo, E1Hi, E1Lo, PkS, PkU);

    k_hyperP<<<3, 256, 0, stream>>>(uHy, iHy, W1, W2, b1, g1, be1, b2, g2, be2, W3, b3,
                                    P, Wf, Wb, flag);
    k_A<<<N_CNT, H_DIM, 0, stream>>>(E1Hi, E1Lo, P, Wf, A);

    int nwaves = B_CNT / 16;                          // 31250
    HyperModel_65755949301857_kernel<<<(nwaves + 3) / 4, 256, 0, stream>>>(
        A, userIdx, servIdx, Wf, Wb, d_out, flag);
}

// Round 13
// 348.775 us; speedup vs baseline: 2.4873x; 1.1566x over previous
//
#include <hip/hip_runtime.h>
#include <hip/hip_bf16.h>

#define U_CNT 339
#define S_CNT 5825
#define N_CNT 6164          // U + S
#define D_DIM 128
#define R_DIM 32
#define B_CNT 500000
#define M_EDGE 400000       // 2*NNZ (symmetrized)
#define H_DIM 64
#define LN_EPS 1e-5f

// ---- transposed E layout: Et[d][col], col(u)=u (0..351 pad), col(s)=352+s ----
#define NPAD 6208           // 352 (u pad) + 5856 (s pad)
#define COL_S0 352
#define ET_U16 (128 * NPAD) // 794,624 ushorts per plane

// ---- adjacency packed as MFMA B-fragments (bf16) ----
#define KT_U 11             // u as K: 352/32
#define KT_S 183            // s as K: 5856/32
#define NT_S 365            // s as N: 5840/16
#define NT_U 22             // u as N: 352/16
#define PKS_U16 (KT_U * NT_S * 512)   // B[k=u][n=s]
#define PKU_U16 (KT_S * NT_U * 512)   // B[k=s][n=u]

#define S_WAVES (8 * NT_S)  // 2920
#define U_WAVES (8 * NT_U)  // 176
#define HOP_BLOCKS ((S_WAVES + U_WAVES) / 4)   // 774 exactly

// fp32 weight-block offsets (elements)
#define WF_B1   4096
#define WF_G1   4160
#define WF_BE1  4224
#define WF_B2   4288
#define WF_G2   4352
#define WF_BE2  4416
#define WF_W3   4480
#define WF_B3   4544
#define WF_TOT  4545

typedef __hip_bfloat16 bf16;
typedef __attribute__((ext_vector_type(8))) short sh8;   // 8 bf16 (MFMA A/B frag)
typedef __attribute__((ext_vector_type(4))) float f4v;   // MFMA C/D frag

__device__ __forceinline__ float b2f(bf16 x) { return __bfloat162float(x); }
__device__ __forceinline__ unsigned short f2bs(float f) {
    union { bf16 b; unsigned short s; } u;
    u.b = __float2bfloat16(f);
    return u.s;
}
__device__ __forceinline__ float bu2f(unsigned int lo16) {   // bf16 bits -> f32
    return __uint_as_float(lo16 << 16);
}
__device__ __forceinline__ float ldf(const void* p, long i, int isf32) {
    return isf32 ? ((const float*)p)[i] : b2f(((const bf16*)p)[i]);
}

// ---------- dtype detect only (adjacency zeroing now via hipMemsetAsync) ----------
__global__ void k_detect(const void* __restrict__ uE, int* __restrict__ flag) {
    const unsigned short* p = (const unsigned short*)uE;
    unsigned short v = p[2 * threadIdx.x];
    int e = (v >> 7) & 0xFF;
    unsigned long long m = __ballot(e >= 127);
    if (threadIdx.x == 0) flag[0] = (m != 0ull) ? 1 : 0;  // 1 => fp32 buffers
}

// ---------- pre: E -> transposed hi/lo planes (LDS transpose) + edge pack ----------
__global__ void __launch_bounds__(256)
k_pre(const void* __restrict__ uE, const void* __restrict__ iE,
      unsigned short* __restrict__ EtHi, unsigned short* __restrict__ EtLo,
      const int* __restrict__ rows, const int* __restrict__ cols,
      const void* __restrict__ vals,
      unsigned short* __restrict__ PkS, unsigned short* __restrict__ PkU,
      const int* __restrict__ flag) {
    __shared__ float ls[32 * 129];                    // padded: conflict-free
    int tid = threadIdx.x;
    int isf32 = flag[0];
    if (blockIdx.x < 193) {                           // node-transpose role
        int ng0 = blockIdx.x * 32;
        int nl = tid >> 3, dbase = (tid & 7) * 16;
        int node = ng0 + nl;
        #pragma unroll
        for (int i = 0; i < 16; ++i) {
            int d = dbase + i;
            float v = 0.f;
            if (node < N_CNT) {
                v = (node < U_CNT) ? ldf(uE, (long)node * D_DIM + d, isf32)
                                   : ldf(iE, (long)(node - U_CNT) * D_DIM + d, isf32);
            }
            ls[nl * 129 + d] = v;
        }
        __syncthreads();
        int nl2 = tid & 31;
        int node2 = ng0 + nl2;
        int c = (node2 < U_CNT) ? node2 : COL_S0 + (node2 - U_CNT);
        #pragma unroll
        for (int i = 0; i < 16; ++i) {
            int d = (tid >> 5) * 16 + i;
            float v = ls[nl2 * 129 + d];
            unsigned short hi = f2bs(v);
            unsigned short lo = f2bs(v - bu2f(hi));
            EtHi[d * NPAD + c] = hi;
            EtLo[d * NPAD + c] = lo;
        }
    }
    // edge packing role (all blocks): only r < U edges carry both orientations
    int e = blockIdx.x * 256 + tid;
    if (e < M_EDGE) {
        int r = rows[e];
        if (r < U_CNT) {
            int u = r, s = cols[e] - U_CNT;
            unsigned short w = f2bs(ldf(vals, e, isf32));
            int kt = u >> 5, kq = (u >> 3) & 3, j = u & 7;
            int nt = s >> 4, nn = s & 15;
            PkS[((kt * NT_S + nt) * 64 + kq * 16 + nn) * 8 + j] = w;
            int kt2 = s >> 5, kq2 = (s >> 3) & 3, j2 = s & 7;
            int nt2 = u >> 4, nn2 = u & 15;
            PkU[((kt2 * NT_U + nt2) * 64 + kq2 * 16 + nn2) * 8 + j2] = w;
        }
    }
}

// ---------- one GCN hop: MFMA GEMM, split-precision E (hi+lo bf16) ----------
__global__ void __launch_bounds__(256)
k_hop(const unsigned short* __restrict__ EinHi, const unsigned short* __restrict__ EinLo,
      unsigned short* __restrict__ EoutHi, unsigned short* __restrict__ EoutLo,
      const unsigned short* __restrict__ PkS, const unsigned short* __restrict__ PkU) {
    int wid = blockIdx.x * 4 + (threadIdx.x >> 6);
    int lane = threadIdx.x & 63;
    int am = lane & 15, aq = lane >> 4;
    f4v acc = {0.f, 0.f, 0.f, 0.f};
    int outcol, d0;
    if (wid < S_WAVES) {
        int mt = wid / NT_S, nt = wid % NT_S;
        d0 = mt * 16;
        const unsigned short* arowH = EinHi + (size_t)(d0 + am) * NPAD;
        const unsigned short* arowL = EinLo + (size_t)(d0 + am) * NPAD;
        const sh8* Bp = (const sh8*)PkS;
        #pragma unroll
        for (int kt = 0; kt < KT_U; ++kt) {
            sh8 ah = *(const sh8*)(arowH + kt * 32 + aq * 8);
            sh8 al = *(const sh8*)(arowL + kt * 32 + aq * 8);
            sh8 bb = Bp[(kt * NT_S + nt) * 64 + lane];
            acc = __builtin_amdgcn_mfma_f32_16x16x32_bf16(ah, bb, acc, 0, 0, 0);
            acc = __builtin_amdgcn_mfma_f32_16x16x32_bf16(al, bb, acc, 0, 0, 0);
        }
        outcol = COL_S0 + nt * 16 + am;
    } else {
        int wid2 = wid - S_WAVES;
        int mt = wid2 / NT_U, nt = wid2 % NT_U;
        d0 = mt * 16;
        const unsigned short* arowH = EinHi + (size_t)(d0 + am) * NPAD + COL_S0;
        const unsigned short* arowL = EinLo + (size_t)(d0 + am) * NPAD + COL_S0;
        const sh8* Bp = (const sh8*)PkU;
        #pragma unroll 4
        for (int kt = 0; kt < KT_S; ++kt) {
            sh8 ah = *(const sh8*)(arowH + kt * 32 + aq * 8);
            sh8 al = *(const sh8*)(arowL + kt * 32 + aq * 8);
            sh8 bb = Bp[(kt * NT_U + nt) * 64 + lane];
            acc = __builtin_amdgcn_mfma_f32_16x16x32_bf16(ah, bb, acc, 0, 0, 0);
            acc = __builtin_amdgcn_mfma_f32_16x16x32_bf16(al, bb, acc, 0, 0, 0);
        }
        outcol = nt * 16 + am;
    }
    #pragma unroll
    for (int reg = 0; reg < 4; ++reg) {
        int d = d0 + aq * 4 + reg;
        float v = acc[reg];
        unsigned short hi = f2bs(v);
        unsigned short lo = f2bs(v - bu2f(hi));
        EoutHi[(size_t)d * NPAD + outcol] = hi;
        EoutLo[(size_t)d * NPAD + outcol] = lo;
    }
}

// ---------- hyperP: blocks 0..7 = P col-slices (LDS-staged, branch hoisted);
//            block 8 = weight prep ----------
// R12 post-mortem: old 3-block version was 70us -- the isf32 branch inside
// the K-loop blocked load pipelining (1 L2 round-trip per iteration) and only
// 2 CUs worked. Now: dtype branch hoisted to staging, all compute from LDS,
// 8 blocks (col j of P needs only col j of T -> embarrassingly col-parallel).
__global__ void __launch_bounds__(256)
k_hyperP(const void* __restrict__ uHy, const void* __restrict__ iHy,
         const void* __restrict__ W1, const void* __restrict__ W2,
         const void* __restrict__ b1, const void* __restrict__ g1,
         const void* __restrict__ be1, const void* __restrict__ b2,
         const void* __restrict__ g2, const void* __restrict__ be2,
         const void* __restrict__ W3, const void* __restrict__ b3,
         float* __restrict__ P, float* __restrict__ Wf,
         unsigned short* __restrict__ Wb,
         const int* __restrict__ flag) {
    int isf32 = flag[0];
    int tid = threadIdx.x;
    if (blockIdx.x == 8) {                            // weight prep
        for (int i = tid; i < 4096; i += 256) {
            int j = i & 7, lane = (i >> 3) & 63, kh = (i >> 9) & 1, t = i >> 10;
            int k = kh * 32 + ((lane >> 4) & 3) * 8 + j;
            int n = t * 16 + (lane & 15);
            Wb[i] = f2bs(ldf(W2, k * 64 + n, isf32));
        }
        for (int i = tid; i < WF_TOT - 4096; i += 256) {
            int g = 4096 + i;
            float v;
            if      (g < WF_G1)  v = ldf(b1,  g - WF_B1,   isf32);
            else if (g < WF_BE1) v = ldf(g1,  g - WF_G1,   isf32);
            else if (g < WF_B2)  v = ldf(be1, g - WF_BE1,  isf32);
            else if (g < WF_G2)  v = ldf(b2,  g - WF_B2,   isf32);
            else if (g < WF_BE2) v = ldf(g2,  g - WF_G2,   isf32);
            else if (g < WF_W3)  v = ldf(be2, g - WF_BE2,  isf32);
            else if (g < WF_B3)  v = ldf(W3,  g - WF_W3,   isf32);
            else                 v = ldf(b3,  0,           isf32);
            Wf[g] = v;
        }
        return;
    }
    int side = blockIdx.x >> 2;                       // 0 = user, 1 = service
    int j0 = (blockIdx.x & 3) * 16;                   // 16 P-columns per block
    const void* Hy = side ? iHy : uHy;                // [32][128]
    long wbase = (long)side * D_DIM * H_DIM;
    __shared__ float Hs[R_DIM * 129];                 // padded rows: 16.5 KB
    __shared__ float Ws[D_DIM * 16];                  // 8 KB (col slice of W1part)
    __shared__ float Ts[R_DIM * 16];                  // 2 KB
    // stage Hy (branch hoisted, coalesced)
    if (isf32) {
        const float* H = (const float*)Hy;
        for (int i = tid; i < R_DIM * D_DIM; i += 256)
            Hs[(i >> 7) * 129 + (i & 127)] = H[i];
    } else {
        const unsigned short* H = (const unsigned short*)Hy;
        for (int i = tid; i < R_DIM * D_DIM; i += 256)
            Hs[(i >> 7) * 129 + (i & 127)] = bu2f(H[i]);
    }
    // stage W1part cols j0..j0+15
    if (isf32) {
        const float* Wp = (const float*)W1 + wbase;
        for (int i = tid; i < D_DIM * 16; i += 256)
            Ws[i] = Wp[(i >> 4) * H_DIM + j0 + (i & 15)];
    } else {
        const unsigned short* Wp = (const unsigned short*)W1 + wbase;
        for (int i = tid; i < D_DIM * 16; i += 256)
            Ws[i] = bu2f(Wp[(i >> 4) * H_DIM + j0 + (i & 15)]);
    }
    __syncthreads();
    // T[a][j] = sum_d Hy[a][d] * W1[d][j0+j]   (512 outputs, 2/thread)
    for (int idx = tid; idx < R_DIM * 16; idx += 256) {
        int a = idx >> 4, j = idx & 15;
        float acc = 0.f;
        #pragma unroll 8
        for (int d = 0; d < D_DIM; ++d)
            acc = fmaf(Hs[a * 129 + d], Ws[d * 16 + j], acc);
        Ts[idx] = acc;
    }
    __syncthreads();
    // P[d][j0+j] = sum_a Hy[a][d] * T[a][j]   (2048 outputs, 8/thread)
    for (int idx = tid; idx < D_DIM * 16; idx += 256) {
        int d = idx >> 4, j = idx & 15;
        float acc = 0.f;
        #pragma unroll
        for (int a = 0; a < R_DIM; ++a)
            acc = fmaf(Hs[a * 129 + d], Ts[a * 16 + j], acc);
        P[side * D_DIM * H_DIM + d * H_DIM + j0 + j] = acc;
    }
}

// ---------- A[r,:] = E[r,:] @ P(side) (+ b1), reading transposed hi/lo E ----------
__global__ void k_A(const unsigned short* __restrict__ EtHi,
                    const unsigned short* __restrict__ EtLo,
                    const float* __restrict__ P, const float* __restrict__ Wf,
                    float* __restrict__ A) {
    int r = blockIdx.x;
    int j = threadIdx.x;                              // 64 threads
    int c = (r < U_CNT) ? r : COL_S0 + (r - U_CNT);
    const float* Pr = P + ((r < U_CNT) ? 0 : D_DIM * H_DIM);
    float acc = (r < U_CNT) ? Wf[WF_B1 + j] : 0.f;
    #pragma unroll 8
    for (int d = 0; d < D_DIM; ++d) {
        float e = bu2f(EtHi[(size_t)d * NPAD + c]) + bu2f(EtLo[(size_t)d * NPAD + c]);
        acc = fmaf(e, Pr[d * H_DIM + j], acc);
    }
    A[r * H_DIM + j] = acc;
}

// ---------- fused MLP via MFMA (R9-verified, unchanged) ----------
__global__ void __launch_bounds__(256)
HyperModel_65755949301857_kernel(
      const float* __restrict__ A, const int* __restrict__ userIdx,
      const int* __restrict__ servIdx, const float* __restrict__ Wf,
      const unsigned short* __restrict__ Wb,
      void* __restrict__ out, const int* __restrict__ flag) {
    int tid = threadIdx.x;
    int wave = tid >> 6, lane = tid & 63;
    long b0 = ((long)blockIdx.x * 4 + wave) * 16;
    if (b0 >= B_CNT) return;
    int isf32 = flag[0];
    int m = lane & 15, quad = lane >> 4;

    int r = (int)b0 + m;
    int ui = userIdx[r];
    int si = servIdx[r] + U_CNT;
    const float* Aur = A + (long)ui * 64;
    const float* Asr = A + (long)si * 64;

    float4 ul0 = *(const float4*)(Aur + quad * 8);
    float4 ul1 = *(const float4*)(Aur + quad * 8 + 4);
    float4 uh0 = *(const float4*)(Aur + 32 + quad * 8);
    float4 uh1 = *(const float4*)(Aur + 32 + quad * 8 + 4);
    float4 sl0 = *(const float4*)(Asr + quad * 8);
    float4 sl1 = *(const float4*)(Asr + quad * 8 + 4);
    float4 sh0 = *(const float4*)(Asr + 32 + quad * 8);
    float4 sh1 = *(const float4*)(Asr + 32 + quad * 8 + 4);
    float zl[8], zh[8];
    zl[0] = ul0.x + sl0.x; zl[1] = ul0.y + sl0.y; zl[2] = ul0.z + sl0.z; zl[3] = ul0.w + sl0.w;
    zl[4] = ul1.x + sl1.x; zl[5] = ul1.y + sl1.y; zl[6] = ul1.z + sl1.z; zl[7] = ul1.w + sl1.w;
    zh[0] = uh0.x + sh0.x; zh[1] = uh0.y + sh0.y; zh[2] = uh0.z + sh0.z; zh[3] = uh0.w + sh0.w;
    zh[4] = uh1.x + sh1.x; zh[5] = uh1.y + sh1.y; zh[6] = uh1.z + sh1.z; zh[7] = uh1.w + sh1.w;

    float s = 0.f, q = 0.f;
    #pragma unroll
    for (int j = 0; j < 8; ++j) {
        s += zl[j] + zh[j];
        q = fmaf(zl[j], zl[j], q);
        q = fmaf(zh[j], zh[j], q);
    }
    s += __shfl_xor(s, 16, 64); s += __shfl_xor(s, 32, 64);
    q += __shfl_xor(q, 16, 64); q += __shfl_xor(q, 32, 64);
    float mu = s * (1.f / 64.f);
    float rs = rsqrtf(q * (1.f / 64.f) - mu * mu + LN_EPS);
    float nm = -mu * rs;

    const float* G1l = Wf + WF_G1 + quad * 8;
    const float* BE1l = Wf + WF_BE1 + quad * 8;
    sh8 a0, a1;
    #pragma unroll
    for (int j = 0; j < 8; ++j) {
        float h0 = fmaxf(fmaf(fmaf(zl[j], rs, nm), G1l[j],      BE1l[j]),      0.f);
        float h1 = fmaxf(fmaf(fmaf(zh[j], rs, nm), G1l[32 + j], BE1l[32 + j]), 0.f);
        a0[j] = (short)f2bs(h0);
        a1[j] = (short)f2bs(h1);
    }

    const sh8* Bp = (const sh8*)Wb;
    sh8 b00 = Bp[0 * 64 + lane], b01 = Bp[1 * 64 + lane];
    sh8 b10 = Bp[2 * 64 + lane], b11 = Bp[3 * 64 + lane];
    sh8 b20 = Bp[4 * 64 + lane], b21 = Bp[5 * 64 + lane];
    sh8 b30 = Bp[6 * 64 + lane], b31 = Bp[7 * 64 + lane];
    f4v acc0 = {0.f, 0.f, 0.f, 0.f}, acc1 = acc0, acc2 = acc0, acc3 = acc0;
    acc0 = __builtin_amdgcn_mfma_f32_16x16x32_bf16(a0, b00, acc0, 0, 0, 0);
    acc0 = __builtin_amdgcn_mfma_f32_16x16x32_bf16(a1, b01, acc0, 0, 0, 0);
    acc1 = __builtin_amdgcn_mfma_f32_16x16x32_bf16(a0, b10, acc1, 0, 0, 0);
    acc1 = __builtin_amdgcn_mfma_f32_16x16x32_bf16(a1, b11, acc1, 0, 0, 0);
    acc2 = __builtin_amdgcn_mfma_f32_16x16x32_bf16(a0, b20, acc2, 0, 0, 0);
    acc2 = __builtin_amdgcn_mfma_f32_16x16x32_bf16(a1, b21, acc2, 0, 0, 0);
    acc3 = __builtin_amdgcn_mfma_f32_16x16x32_bf16(a0, b30, acc3, 0, 0, 0);
    acc3 = __builtin_amdgcn_mfma_f32_16x16x32_bf16(a1, b31, acc3, 0, 0, 0);

    float b2c0 = Wf[WF_B2 + 0 * 16 + m], b2c1 = Wf[WF_B2 + 1 * 16 + m];
    float b2c2 = Wf[WF_B2 + 2 * 16 + m], b2c3 = Wf[WF_B2 + 3 * 16 + m];
    float y0[4], y1[4], y2[4], y3[4];
    float srow[4], qrow[4];
    #pragma unroll
    for (int reg = 0; reg < 4; ++reg) {
        y0[reg] = acc0[reg] + b2c0;
        y1[reg] = acc1[reg] + b2c1;
        y2[reg] = acc2[reg] + b2c2;
        y3[reg] = acc3[reg] + b2c3;
        srow[reg] = (y0[reg] + y1[reg]) + (y2[reg] + y3[reg]);
        float qa = y0[reg] * y0[reg];
        qa = fmaf(y1[reg], y1[reg], qa);
        qa = fmaf(y2[reg], y2[reg], qa);
        qa = fmaf(y3[reg], y3[reg], qa);
        qrow[reg] = qa;
    }
    #pragma unroll
    for (int off = 1; off < 16; off <<= 1) {
        #pragma unroll
        for (int reg = 0; reg < 4; ++reg) {
            srow[reg] += __shfl_xor(srow[reg], off, 64);
            qrow[reg] += __shfl_xor(qrow[reg], off, 64);
        }
    }

    float g2c0 = Wf[WF_G2 + m],      g2c1 = Wf[WF_G2 + 16 + m];
    float g2c2 = Wf[WF_G2 + 32 + m], g2c3 = Wf[WF_G2 + 48 + m];
    float e2c0 = Wf[WF_BE2 + m],      e2c1 = Wf[WF_BE2 + 16 + m];
    float e2c2 = Wf[WF_BE2 + 32 + m], e2c3 = Wf[WF_BE2 + 48 + m];
    float w3c0 = Wf[WF_W3 + m],      w3c1 = Wf[WF_W3 + 16 + m];
    float w3c2 = Wf[WF_W3 + 32 + m], w3c3 = Wf[WF_W3 + 48 + m];
    float b3v = Wf[WF_B3];
    float o[4];
    #pragma unroll
    for (int reg = 0; reg < 4; ++reg) {
        float mu2 = srow[reg] * (1.f / 64.f);
        float rs2 = rsqrtf(qrow[reg] * (1.f / 64.f) - mu2 * mu2 + LN_EPS);
        float nm2 = -mu2 * rs2;
        float t0 = fmaxf(fmaf(fmaf(y0[reg], rs2, nm2), g2c0, e2c0), 0.f);
        float t1 = fmaxf(fmaf(fmaf(y1[reg], rs2, nm2), g2c1, e2c1), 0.f);
        float t2 = fmaxf(fmaf(fmaf(y2[reg], rs2, nm2), g2c2, e2c2), 0.f);
        float t3 = fmaxf(fmaf(fmaf(y3[reg], rs2, nm2), g2c3, e2c3), 0.f);
        o[reg] = fmaf(t0, w3c0, fmaf(t1, w3c1, fmaf(t2, w3c2, t3 * w3c3)));
    }
    #pragma unroll
    for (int off = 1; off < 16; off <<= 1) {
        #pragma unroll
        for (int reg = 0; reg < 4; ++reg) o[reg] += __shfl_xor(o[reg], off, 64);
    }
    if (m == 0) {
        long rb = b0 + quad * 4;
        if (isf32) {
            float4 v = make_float4(o[0] + b3v, o[1] + b3v, o[2] + b3v, o[3] + b3v);
            *(float4*)((float*)out + rb) = v;
        } else {
            ushort4 v;
            v.x = f2bs(o[0] + b3v);
            v.y = f2bs(o[1] + b3v);
            v.z = f2bs(o[2] + b3v);
            v.w = f2bs(o[3] + b3v);
            *(ushort4*)((bf16*)out + rb) = v;
        }
    }
}

extern "C" __attribute__((visibility("default")))
void kernel_launch(void* const* d_in, const int* in_sizes, int n_in,
                   void* d_out, int out_size, void* d_ws, size_t ws_size,
                   hipStream_t stream) {
    const void* uE   = d_in[0];
    const void* iE   = d_in[1];
    const void* uHy  = d_in[2];
    const void* iHy  = d_in[3];
    const void* W1   = d_in[4];
    const void* b1   = d_in[5];
    const void* g1   = d_in[6];
    const void* be1  = d_in[7];
    const void* W2   = d_in[8];
    const void* b2   = d_in[9];
    const void* g2   = d_in[10];
    const void* be2  = d_in[11];
    const void* W3   = d_in[12];
    const void* b3   = d_in[13];
    const void* adj_vals = d_in[14];
    const int*  adj_rows = (const int*)d_in[15];
    const int*  adj_cols = (const int*)d_in[16];
    const int*  userIdx  = (const int*)d_in[17];
    const int*  servIdx  = (const int*)d_in[18];

    char* w = (char*)d_ws;
    size_t off = 0;
    auto alloc = [&](size_t bytes) -> char* {
        char* p = w + off;
        off += (bytes + 255) & ~(size_t)255;
        return p;
    };
    unsigned short* E0Hi = (unsigned short*)alloc((size_t)ET_U16 * 2);
    unsigned short* E0Lo = (unsigned short*)alloc((size_t)ET_U16 * 2);
    unsigned short* E1Hi = (unsigned short*)alloc((size_t)ET_U16 * 2);
    unsigned short* E1Lo = (unsigned short*)alloc((size_t)ET_U16 * 2);
    unsigned short* PkS  = (unsigned short*)alloc((size_t)PKS_U16 * 2);
    unsigned short* PkU  = (unsigned short*)alloc((size_t)PKU_U16 * 2);
    float* P    = (float*)alloc((size_t)2 * D_DIM * H_DIM * 4);
    float* A    = (float*)alloc((size_t)N_CNT * H_DIM * 4);
    int*   flag = (int*)alloc(256);
    float* Wf   = (float*)alloc((size_t)WF_TOT * 4);
    unsigned short* Wb = (unsigned short*)alloc((size_t)4096 * 2);

    k_detect<<<1, 64, 0, stream>>>(uE, flag);
    hipMemsetAsync(PkS, 0, (size_t)PKS_U16 * 2, stream);
    hipMemsetAsync(PkU, 0, (size_t)PKU_U16 * 2, stream);
    k_pre<<<(M_EDGE + 255) / 256, 256, 0, stream>>>(uE, iE, E0Hi, E0Lo,
                                                    adj_rows, adj_cols, adj_vals,
                                                    PkS, PkU, flag);
    // 3 hops: E0 -> E1 -> E0 -> E1 (MFMA GEMM, split-precision)
    k_hop<<<HOP_BLOCKS, 256, 0, stream>>>(E0Hi, E0Lo, E1Hi, E1Lo, PkS, PkU);
    k_hop<<<HOP_BLOCKS, 256, 0, stream>>>(E1Hi, E1Lo, E0Hi, E0Lo, PkS, PkU);
    k_hop<<<HOP_BLOCKS, 256, 0, stream>>>(E0Hi, E0Lo, E1Hi, E1Lo, PkS, PkU);

    k_hyperP<<<9, 256, 0, stream>>>(uHy, iHy, W1, W2, b1, g1, be1, b2, g2, be2, W3, b3,
                                    P, Wf, Wb, flag);
    k_A<<<N_CNT, H_DIM, 0, stream>>>(E1Hi, E1Lo, P, Wf, A);

    int nwaves = B_CNT / 16;                          // 31250
    HyperModel_65755949301857_kernel<<<(nwaves + 3) / 4, 256, 0, stream>>>(
        A, userIdx, servIdx, Wf, Wb, d_out, flag);
}